// Round 1
// baseline (1131.183 us; speedup 1.0000x reference)
//
#include <hip/hip_runtime.h>
#include <math.h>

#define NB   8
#define TT   400
#define HH   128
#define CC   96
#define DD   4096
#define THRV (1.0f - 1e-5f)
#define XR   40      // f16 row pad: 80 B rows (5*16B -> b128-aligned, 2-way banks only)
#define HEPS 4e-6f   // convergence tolerance (same class-proven margin as before)

typedef _Float16 f16x8 __attribute__((ext_vector_type(8)));
typedef float    f32x4 __attribute__((ext_vector_type(4)));

__device__ __forceinline__ float sigm(float v) { return 1.0f / (1.0f + expf(-v)); }

__device__ __forceinline__ void split2(float4 u0, float4 u1, f16x8& hi, f16x8& lo) {
    float x[8] = {u0.x, u0.y, u0.z, u0.w, u1.x, u1.y, u1.z, u1.w};
    #pragma unroll
    for (int e = 0; e < 8; ++e) {
        _Float16 h = (_Float16)x[e];
        hi[e] = h;
        lo[e] = (_Float16)(x[e] - (float)h);
    }
}
__device__ __forceinline__ void split1(float x, _Float16& hi, _Float16& lo) {
    hi = (_Float16)x;
    lo = (_Float16)(x - (float)hi);
}

// lane ^ 32 combine on the VALU pipe (keeps the LDS pipe free)
__device__ __forceinline__ float xsum32(float v) {
#if __has_builtin(__builtin_amdgcn_permlane32_swap)
    auto r = __builtin_amdgcn_permlane32_swap(__float_as_uint(v), __float_as_uint(v), false, false);
    return __uint_as_float(r[0]) + __uint_as_float(r[1]);
#else
    return v + __shfl_xor(v, 32, 64);
#endif
}
__device__ __forceinline__ float xmax32(float v) {
#if __has_builtin(__builtin_amdgcn_permlane32_swap)
    auto r = __builtin_amdgcn_permlane32_swap(__float_as_uint(v), __float_as_uint(v), false, false);
    return fmaxf(__uint_as_float(r[0]), __uint_as_float(r[1]));
#else
    return fmaxf(v, __shfl_xor(v, 32, 64));
#endif
}

// full-row normalized write of chars at time TME from chs[SLOT]; wave w owns row m=w
#define OUTROW(SLOT, TME)                                                        \
    do {                                                                         \
        const float* cr_ = &chs[SLOT][w][0];                                     \
        float v0_ = cr_[lane];                                                   \
        float v1_ = (lane < 32) ? cr_[64 + lane] : -INFINITY;                    \
        float mx_ = xmax32(fmaxf(v0_, v1_));                                     \
        mx_ = fmaxf(mx_, __shfl_xor(mx_, 16, 64));                               \
        mx_ = fmaxf(mx_, __shfl_xor(mx_, 8, 64));                                \
        mx_ = fmaxf(mx_, __shfl_xor(mx_, 4, 64));                                \
        mx_ = fmaxf(mx_, __shfl_xor(mx_, 2, 64));                                \
        mx_ = fmaxf(mx_, __shfl_xor(mx_, 1, 64));                                \
        float q0_ = v0_ / mx_;                                                   \
        size_t base_ = ((size_t)(b0 + w) * TT + (TME)) * CC;                     \
        out[base_ + lane] = (q0_ > THRV) ? q0_ : 0.f;                            \
        if (lane < 32) {                                                         \
            float q1_ = v1_ / mx_;                                               \
            out[base_ + 64 + lane] = (q1_ > THRV) ? q1_ : 0.f;                   \
        }                                                                        \
        float q52_ = __shfl(q0_, 52, 64);                                        \
        if (!found && q52_ == 1.0f) { found = true; len = (TME) + 1; }           \
    } while (0)

__global__ __launch_bounds__(512)
void gru_title(const float* __restrict__ img,
               const float* __restrict__ l1w,
               const float* __restrict__ l1b,
               const float* __restrict__ wih,
               const float* __restrict__ whh,
               const float* __restrict__ bih,
               const float* __restrict__ bhh,
               const float* __restrict__ l2w,
               const float* __restrict__ l2b,
               float* __restrict__ out,
               float* __restrict__ lens)
{
    // M-packed A layout: value (m, k, hi) at row 16*((k>>3)&3)+m, (lo) at +8;
    // f16 col 8*(k>>5)+(k&7).  A-frag read is then simply row=lane, col=8*kt.
    __shared__ alignas(16) _Float16 x2 [2][64][XR];   // h   hi rows 0-7, lo rows 8-15 per 16-group
    __shared__ alignas(16) _Float16 l2v[2][64][XR];   // leaky(h), same layout
    __shared__ alignas(16) float    chs[2][NB][CC];   // chars, parity-buffered
    __shared__ alignas(16) _Float16 bclS[6][4][4][16][8]; // chars lo-weights (24 KB)
    __shared__ alignas(16) float    gsT[4][HH][NB];   // t=0 scalar gate staging
    __shared__ alignas(16) float    xs0[NB][HH];      // x0 (t=0 scalar path)
    __shared__ int sh_st[4];                          // stable flags, 4-slot rotation

    const int tid  = threadIdx.x;
    const int b0   = blockIdx.x * NB;
    const int w    = tid >> 6;     // wave 0..7
    const int lane = tid & 63;
    const int lm   = lane & 15;
    const int lq   = lane >> 4;

    // ---- gate weights: wave w owns ALL 4 gate types for i-chunk [16w,16w+16) ----
    // g=0: r (wih+whh fused, x==h for t>=1); g=1: z (fused); g=2: n_i (wih); g=3: n_h (whh)
    f16x8 bh[4][4], bl[4][4];
    float gb[4];
    const int ic = 16 * w + lm;    // hidden col this lane owns
    #pragma unroll
    for (int g = 0; g < 4; ++g) {
        const float* r0;
        const float* r1 = nullptr;
        float bsum;
        if (g == 0)      { r0 = wih + (size_t)ic * HH;         r1 = whh + (size_t)ic * HH;         bsum = bih[ic] + bhh[ic]; }
        else if (g == 1) { r0 = wih + (size_t)(128 + ic) * HH; r1 = whh + (size_t)(128 + ic) * HH; bsum = bih[128 + ic] + bhh[128 + ic]; }
        else if (g == 2) { r0 = wih + (size_t)(256 + ic) * HH;                                     bsum = bih[256 + ic]; }
        else             { r0 = whh + (size_t)(256 + ic) * HH;                                     bsum = bhh[256 + ic]; }
        gb[g] = bsum;
        #pragma unroll
        for (int kt = 0; kt < 4; ++kt) {
            const int k0 = 32 * kt + 8 * lq;
            float4 u0 = *(const float4*)(r0 + k0);
            float4 u1 = *(const float4*)(r0 + k0 + 4);
            if (r1) {
                float4 e0 = *(const float4*)(r1 + k0);
                float4 e1 = *(const float4*)(r1 + k0 + 4);
                u0.x += e0.x; u0.y += e0.y; u0.z += e0.z; u0.w += e0.w;
                u1.x += e1.x; u1.y += e1.y; u1.z += e1.z; u1.w += e1.w;
            }
            split2(u0, u1, bh[g][kt], bl[g][kt]);
        }
    }

    // ---- chars: waves 1,3,5 own 2 col-tiles each; hi in regs, lo in LDS ----
    const int cw = (w == 1) ? 0 : (w == 3) ? 1 : (w == 5) ? 2 : -1;
    f16x8 bch[2][4];
    float cb[2] = {0.f, 0.f};
    if (cw >= 0) {
        #pragma unroll
        for (int u = 0; u < 2; ++u) {
            const int n = 16 * (2 * cw + u) + lm;
            cb[u] = l2b[n];
            #pragma unroll
            for (int kt = 0; kt < 4; ++kt) {
                const int k0 = 32 * kt + 8 * lq;
                float4 u0 = *(const float4*)(l2w + (size_t)n * HH + k0);
                float4 u1 = *(const float4*)(l2w + (size_t)n * HH + k0 + 4);
                f16x8 hi, lo;
                split2(u0, u1, hi, lo);
                bch[u][kt] = hi;
            }
        }
    }
    // stash chars lo-weights in LDS (all threads help)
    for (int idx = tid; idx < 6 * 4 * 4 * 16; idx += 512) {
        int t_  = idx;
        int lm_ = t_ & 15; t_ >>= 4;
        int lq_ = t_ & 3;  t_ >>= 2;
        int kt_ = t_ & 3;  t_ >>= 2;
        int ct_ = t_;                       // 0..5
        const int n  = 16 * ct_ + lm_;
        const int k0 = 32 * kt_ + 8 * lq_;
        #pragma unroll
        for (int e = 0; e < 8; ++e) {
            float v = l2w[(size_t)n * HH + k0 + e];
            _Float16 hi = (_Float16)v;
            bclS[ct_][kt_][lq_][lm_][e] = (_Float16)(v - (float)hi);
        }
    }

    if (tid < 4) sh_st[tid] = 1;

    // ---- prologue: x0 = leaky(img @ l1w.T + l1b), exact f32, 2 cols/thread ----
    {
        const int m  = tid >> 6;
        const int cp = (tid & 63) * 2;
        const float4* xp = (const float4*)(img + (size_t)(b0 + m) * DD);
        #pragma unroll
        for (int cc2 = 0; cc2 < 2; ++cc2) {
            const int c = cp + cc2;
            const float4* wp = (const float4*)(l1w + (size_t)c * DD);
            float a0 = 0.f, a1 = 0.f;
            #pragma unroll 4
            for (int k = 0; k < DD / 4; k += 2) {
                float4 w0 = wp[k], w1 = wp[k + 1];
                float4 u0 = xp[k], u1 = xp[k + 1];
                a0 += w0.x * u0.x + w0.y * u0.y + w0.z * u0.z + w0.w * u0.w;
                a1 += w1.x * u1.x + w1.y * u1.y + w1.z * u1.z + w1.w * u1.w;
            }
            float h0 = a0 + a1 + l1b[c];
            xs0[m][c] = (h0 >= 0.f) ? h0 : 0.01f * h0;
        }
    }
    __syncthreads();

    // nonlin ownership: lane holds 2 batch rows (mA, mA+1) for hidden ic
    const int mA  = (lane < 32) ? 4 * lq : 4 * (lq - 2) + 2;
    const int iN  = ic;
    const int rB_ = 16 * ((iN >> 3) & 3);
    const int cB_ = 8 * (iN >> 5) + (iN & 7);

    float hA = 0.f, hB = 0.f;
    int  len   = TT;
    bool found = false;
    int  tex   = TT;

    // chars(t-1): M-packed MFMA from l2v[slot] into chs[slot]
    auto chars_step = [&](int slot) {
        if (cw >= 0) {
            f32x4 z4 = {0.f, 0.f, 0.f, 0.f};
            f32x4 cacc0 = z4, cacc1 = z4;
            #pragma unroll
            for (int kt = 0; kt < 4; ++kt) {
                f16x8 cf  = *(const f16x8*)&l2v[slot][lane][8 * kt];
                f16x8 wl0 = *(const f16x8*)&bclS[2 * cw + 0][kt][lq][lm][0];
                f16x8 wl1 = *(const f16x8*)&bclS[2 * cw + 1][kt][lq][lm][0];
                cacc0 = __builtin_amdgcn_mfma_f32_16x16x32_f16(cf, bch[0][kt], cacc0, 0, 0, 0);
                cacc0 = __builtin_amdgcn_mfma_f32_16x16x32_f16(cf, wl0,        cacc0, 0, 0, 0);
                cacc1 = __builtin_amdgcn_mfma_f32_16x16x32_f16(cf, bch[1][kt], cacc1, 0, 0, 0);
                cacc1 = __builtin_amdgcn_mfma_f32_16x16x32_f16(cf, wl1,        cacc1, 0, 0, 0);
            }
            #pragma unroll
            for (int u = 0; u < 2; ++u) {
                f32x4 ca = u ? cacc1 : cacc0;
                const int n = 16 * (2 * cw + u) + lm;
                float s0 = xsum32(ca[0]);
                float s1 = xsum32(ca[1]);
                float s2 = xsum32(ca[2]);
                float s3 = xsum32(ca[3]);
                chs[slot][mA][n]     = ((lane < 32) ? s0 : s2) + cb[u];
                chs[slot][mA + 1][n] = ((lane < 32) ? s1 : s3) + cb[u];
            }
        }
    };

    for (int t = 0; t < TT; ++t) {
        const int pr = (t + 1) & 1;   // read slot  ((t-1)&1)
        const int pc = t & 1;         // write slot; == (t-2)&1 for chs

        float G[4][2];

        if (t == 0) {
            // exact-f32 gates from xs0 (wih only for g<3; h=0 -> g=3 is bias only)
            {
                const int g = tid >> 7;        // 0..3
                const int i = tid & 127;
                float bsum;
                if (g == 0)      bsum = bih[i] + bhh[i];
                else if (g == 1) bsum = bih[128 + i] + bhh[128 + i];
                else if (g == 2) bsum = bih[256 + i];
                else             bsum = bhh[256 + i];
                float accT[NB];
                #pragma unroll
                for (int m = 0; m < NB; ++m) accT[m] = bsum;
                if (g < 3) {
                    const float4* wp = (const float4*)(wih + (size_t)(128 * g + i) * HH);
                    #pragma unroll
                    for (int k = 0; k < HH / 4; ++k) {
                        float4 wv = wp[k];
                        #pragma unroll
                        for (int m = 0; m < NB; ++m) {
                            float4 x = *(const float4*)&xs0[m][4 * k];
                            accT[m] += wv.x * x.x + wv.y * x.y + wv.z * x.z + wv.w * x.w;
                        }
                    }
                }
                float4 lo4 = {accT[0], accT[1], accT[2], accT[3]};
                float4 hi4 = {accT[4], accT[5], accT[6], accT[7]};
                *(float4*)&gsT[g][i][0] = lo4;
                *(float4*)&gsT[g][i][4] = hi4;
            }
            __syncthreads();
            #pragma unroll
            for (int g = 0; g < 4; ++g) {
                float2 p = *(const float2*)&gsT[g][iN][mA];
                G[g][0] = p.x;
                G[g][1] = p.y;
            }
        } else {
            // ---- chars(t-1) (off critical path) ----
            chars_step(pr);
            // ---- full-row write of chars(t-2), all 8 waves ----
            if (t >= 2) OUTROW(pc, t - 2);
            // ---- gates(t): M-packed, 2 MFMA per (g,kt) ----
            f32x4 z4 = {0.f, 0.f, 0.f, 0.f};
            f32x4 acc[4] = {z4, z4, z4, z4};
            #pragma unroll
            for (int kt = 0; kt < 4; ++kt) {
                f16x8 af = *(const f16x8*)&x2[pr][lane][8 * kt];
                #pragma unroll
                for (int g = 0; g < 4; ++g) {
                    acc[g] = __builtin_amdgcn_mfma_f32_16x16x32_f16(af, bh[g][kt], acc[g], 0, 0, 0);
                    acc[g] = __builtin_amdgcn_mfma_f32_16x16x32_f16(af, bl[g][kt], acc[g], 0, 0, 0);
                }
            }
            // combine hi(rows 0-7, lanes<32) + lo(rows 8-15, lanes>=32) + bias
            #pragma unroll
            for (int g = 0; g < 4; ++g) {
                float s0 = xsum32(acc[g][0]);
                float s1 = xsum32(acc[g][1]);
                float s2 = xsum32(acc[g][2]);
                float s3 = xsum32(acc[g][3]);
                G[g][0] = ((lane < 32) ? s0 : s2) + gb[g];
                G[g][1] = ((lane < 32) ? s1 : s3) + gb[g];
            }
        }

        // ---- GRU nonlinearity, fully in-lane, 2 rows/lane ----
        bool chg = (t < 2);
        #pragma unroll
        for (int s = 0; s < 2; ++s) {
            float hp = s ? hB : hA;
            float r  = sigm(G[0][s]);
            float z  = sigm(G[1][s]);
            float n  = tanhf(G[2][s] + r * G[3][s]);
            float h  = (1.f - z) * n + z * hp;
            chg |= (fabsf(h - hp) > HEPS);
            float lv = (h >= 0.f) ? h : 0.01f * h;
            _Float16 a, b;
            split1(h, a, b);
            x2[pc][rB_ + mA + s][cB_]     = a;
            x2[pc][rB_ + 8 + mA + s][cB_] = b;
            split1(lv, a, b);
            l2v[pc][rB_ + mA + s][cB_]     = a;
            l2v[pc][rB_ + 8 + mA + s][cB_] = b;
            if (s) hB = h; else hA = h;
        }
        if (chg) sh_st[t & 3] = 0;              // benign multi-writer race
        if (tid == 0) sh_st[(t + 2) & 3] = 1;   // slot for t+2; 2 barriers from its writers
        __syncthreads();                        // the ONLY barrier per step
        if (t >= 2 && sh_st[t & 3]) { tex = t; break; }
    }

    if (tex == TT) {
        // natural end: write chars(TT-2); compute + write chars(TT-1)
        const int pl = (TT - 1) & 1;
        chars_step(pl);
        OUTROW(TT & 1, TT - 2);
        __syncthreads();
        OUTROW(pl, TT - 1);
    } else {
        // frozen from tex: loop wrote times 0..tex-2. Write chars(tex-1), then
        // fill [tex, TT) with the two parity patterns (zeros included), stride-2.
        OUTROW((tex + 1) & 1, tex - 1);
        size_t rowbase = (size_t)(b0 + w) * TT * CC;
        #pragma unroll
        for (int p = 0; p < 2; ++p) {
            const float* cr = &chs[p][w][0];
            float v0 = cr[lane];
            float v1 = (lane < 32) ? cr[64 + lane] : -INFINITY;
            float mx = xmax32(fmaxf(v0, v1));
            mx = fmaxf(mx, __shfl_xor(mx, 16, 64));
            mx = fmaxf(mx, __shfl_xor(mx, 8, 64));
            mx = fmaxf(mx, __shfl_xor(mx, 4, 64));
            mx = fmaxf(mx, __shfl_xor(mx, 2, 64));
            mx = fmaxf(mx, __shfl_xor(mx, 1, 64));
            const int u0 = tex + (((tex & 1) == p) ? 0 : 1);
            float q0 = v0 / mx;
            float w0v = (q0 > THRV) ? q0 : 0.f;
            float w1v = 0.f;
            if (lane < 32) {
                float q1 = v1 / mx;
                w1v = (q1 > THRV) ? q1 : 0.f;
            }
            for (int u = u0; u < TT; u += 2) {
                out[rowbase + (size_t)u * CC + lane] = w0v;
                if (lane < 32) out[rowbase + (size_t)u * CC + 64 + lane] = w1v;
            }
        }
        // lens: frozen pattern's char-52 hit (if any) recorded at tex-2 / tex-1.
    }

    if (lane == 0) lens[b0 + w] = (float)len;
}

extern "C" void kernel_launch(void* const* d_in, const int* in_sizes, int n_in,
                              void* d_out, int out_size, void* d_ws, size_t ws_size,
                              hipStream_t stream)
{
    const float* img = (const float*)d_in[0];
    const float* l1w = (const float*)d_in[1];
    const float* l1b = (const float*)d_in[2];
    const float* wih = (const float*)d_in[3];
    const float* whh = (const float*)d_in[4];
    const float* bih = (const float*)d_in[5];
    const float* bhh = (const float*)d_in[6];
    const float* l2w = (const float*)d_in[7];
    const float* l2b = (const float*)d_in[8];

    float* out  = (float*)d_out;
    float* lens = out + (size_t)2048 * TT * CC;

    // no memset: the kernel writes every title element exactly once
    // (full-row coalesced stores with explicit zeros) and all lens entries.
    gru_title<<<dim3(2048 / NB), dim3(512), 0, stream>>>(
        img, l1w, l1b, wih, whh, bih, bhh, l2w, l2b, out, lens);
}

// Round 2
// 1119.571 us; speedup vs baseline: 1.0104x; 1.0104x over previous
//
#include <hip/hip_runtime.h>
#include <math.h>

#define NB   8
#define TT   400
#define HH   128
#define CC   96
#define DD   4096
#define THRV (1.0f - 1e-5f)
#define XR   40      // f16 row pad: 80 B rows (5*16B -> b128-aligned, clean bank walk)
#define HEPS 4e-6f   // convergence tolerance (same class-proven margin as before)
#define CHP  128     // chs row stride (padded so lanes>=32 reads stay in-row)

typedef _Float16 f16x8 __attribute__((ext_vector_type(8)));
typedef float    f32x4 __attribute__((ext_vector_type(4)));

__device__ __forceinline__ float rcp_fast(float x) {
#if __has_builtin(__builtin_amdgcn_rcpf)
    return __builtin_amdgcn_rcpf(x);
#else
    return 1.0f / x;
#endif
}
// v_exp_f32-based sigmoid/tanh: ~1e-7 err, far inside the proven 5e-5 margin.
__device__ __forceinline__ float sigm(float v)  { return rcp_fast(1.0f + __expf(-v)); }
__device__ __forceinline__ float ftanh(float x) { return 1.0f - 2.0f * rcp_fast(1.0f + __expf(2.0f * x)); }

__device__ __forceinline__ void split2(float4 u0, float4 u1, f16x8& hi, f16x8& lo) {
    float x[8] = {u0.x, u0.y, u0.z, u0.w, u1.x, u1.y, u1.z, u1.w};
    #pragma unroll
    for (int e = 0; e < 8; ++e) {
        _Float16 h = (_Float16)x[e];
        hi[e] = h;
        lo[e] = (_Float16)(x[e] - (float)h);
    }
}
__device__ __forceinline__ void split1(float x, _Float16& hi, _Float16& lo) {
    hi = (_Float16)x;
    lo = (_Float16)(x - (float)hi);
}

// lane ^ 32 combine on the VALU pipe (keeps the LDS pipe free)
__device__ __forceinline__ float xsum32(float v) {
#if __has_builtin(__builtin_amdgcn_permlane32_swap)
    auto r = __builtin_amdgcn_permlane32_swap(__float_as_uint(v), __float_as_uint(v), false, false);
    return __uint_as_float(r[0]) + __uint_as_float(r[1]);
#else
    return v + __shfl_xor(v, 32, 64);
#endif
}

// Barrier WITHOUT the vmcnt(0) drain __syncthreads would emit: global stores
// (out[]) are fire-and-forget (nothing reads them), so only LDS ops need to
// complete before waves cross. Pattern per the verified 8-phase template.
__device__ __forceinline__ void step_barrier() {
    __builtin_amdgcn_sched_barrier(0);
    asm volatile("s_waitcnt lgkmcnt(0)" ::: "memory");
    __builtin_amdgcn_s_barrier();
    asm volatile("" ::: "memory");
    __builtin_amdgcn_sched_barrier(0);
}

__global__ __launch_bounds__(512)
void gru_title(const float* __restrict__ img,
               const float* __restrict__ l1w,
               const float* __restrict__ l1b,
               const float* __restrict__ wih,
               const float* __restrict__ whh,
               const float* __restrict__ bih,
               const float* __restrict__ bhh,
               const float* __restrict__ l2w,
               const float* __restrict__ l2b,
               float* __restrict__ out,
               float* __restrict__ lens)
{
    // M-packed A layout: value (m, k, hi) at row 16*((k>>3)&3)+m, (lo) at +8;
    // f16 col 8*(k>>5)+(k&7).  A-frag read is then simply row=lane, col=8*kt.
    __shared__ alignas(16) _Float16 x2 [2][64][XR];   // h   hi rows 0-7, lo rows 8-15 per 16-group
    __shared__ alignas(16) _Float16 l2v[2][64][XR];   // leaky(h), same layout
    __shared__ alignas(16) float    chs[2][NB][CHP];  // chars, parity-buffered, padded rows
    __shared__ alignas(16) _Float16 bclS[6][4][4][16][8]; // chars lo-weights (24 KB)
    __shared__ alignas(16) float    gsT[4][HH][NB];   // t=0 scalar gate staging
    __shared__ alignas(16) float    xs0[NB][HH];      // x0 (t=0 scalar path)
    __shared__ int sh_st[4];                          // stable flags, 4-slot rotation

    const int tid  = threadIdx.x;
    const int b0   = blockIdx.x * NB;
    const int w    = tid >> 6;     // wave 0..7
    const int lane = tid & 63;
    const int lm   = lane & 15;
    const int lq   = lane >> 4;

    // ---- gate weights: wave w owns ALL 4 gate types for i-chunk [16w,16w+16) ----
    // g=0: r (wih+whh fused, x==h for t>=1); g=1: z (fused); g=2: n_i (wih); g=3: n_h (whh)
    f16x8 bh[4][4], bl[4][4];
    float gb[4];
    const int ic = 16 * w + lm;    // hidden col this lane owns
    #pragma unroll
    for (int g = 0; g < 4; ++g) {
        const float* r0;
        const float* r1 = nullptr;
        float bsum;
        if (g == 0)      { r0 = wih + (size_t)ic * HH;         r1 = whh + (size_t)ic * HH;         bsum = bih[ic] + bhh[ic]; }
        else if (g == 1) { r0 = wih + (size_t)(128 + ic) * HH; r1 = whh + (size_t)(128 + ic) * HH; bsum = bih[128 + ic] + bhh[128 + ic]; }
        else if (g == 2) { r0 = wih + (size_t)(256 + ic) * HH;                                     bsum = bih[256 + ic]; }
        else             { r0 = whh + (size_t)(256 + ic) * HH;                                     bsum = bhh[256 + ic]; }
        gb[g] = bsum;
        #pragma unroll
        for (int kt = 0; kt < 4; ++kt) {
            const int k0 = 32 * kt + 8 * lq;
            float4 u0 = *(const float4*)(r0 + k0);
            float4 u1 = *(const float4*)(r0 + k0 + 4);
            if (r1) {
                float4 e0 = *(const float4*)(r1 + k0);
                float4 e1 = *(const float4*)(r1 + k0 + 4);
                u0.x += e0.x; u0.y += e0.y; u0.z += e0.z; u0.w += e0.w;
                u1.x += e1.x; u1.y += e1.y; u1.z += e1.z; u1.w += e1.w;
            }
            split2(u0, u1, bh[g][kt], bl[g][kt]);
        }
    }

    // ---- chars: waves 1,3,6 (distinct SIMDs) own 2 col-tiles each ----
    const int cw = (w == 1) ? 0 : (w == 3) ? 1 : (w == 6) ? 2 : -1;
    f16x8 bch[2][4];
    float cb[2] = {0.f, 0.f};
    if (cw >= 0) {
        #pragma unroll
        for (int u = 0; u < 2; ++u) {
            const int n = 16 * (2 * cw + u) + lm;
            cb[u] = l2b[n];
            #pragma unroll
            for (int kt = 0; kt < 4; ++kt) {
                const int k0 = 32 * kt + 8 * lq;
                float4 u0 = *(const float4*)(l2w + (size_t)n * HH + k0);
                float4 u1 = *(const float4*)(l2w + (size_t)n * HH + k0 + 4);
                f16x8 hi, lo;
                split2(u0, u1, hi, lo);
                bch[u][kt] = hi;
            }
        }
    }
    // stash chars lo-weights in LDS (all threads help)
    for (int idx = tid; idx < 6 * 4 * 4 * 16; idx += 512) {
        int t_  = idx;
        int lm_ = t_ & 15; t_ >>= 4;
        int lq_ = t_ & 3;  t_ >>= 2;
        int kt_ = t_ & 3;  t_ >>= 2;
        int ct_ = t_;                       // 0..5
        const int n  = 16 * ct_ + lm_;
        const int k0 = 32 * kt_ + 8 * lq_;
        #pragma unroll
        for (int e = 0; e < 8; ++e) {
            float v = l2w[(size_t)n * HH + k0 + e];
            _Float16 hi = (_Float16)v;
            bclS[ct_][kt_][lq_][lm_][e] = (_Float16)(v - (float)hi);
        }
    }

    if (tid < 4) sh_st[tid] = 1;

    // ---- prologue: x0 = leaky(img @ l1w.T + l1b), exact f32, 2 cols/thread ----
    {
        const int m  = tid >> 6;
        const int cp = (tid & 63) * 2;
        const float4* xp = (const float4*)(img + (size_t)(b0 + m) * DD);
        #pragma unroll
        for (int cc2 = 0; cc2 < 2; ++cc2) {
            const int c = cp + cc2;
            const float4* wp = (const float4*)(l1w + (size_t)c * DD);
            float a0 = 0.f, a1 = 0.f;
            #pragma unroll 4
            for (int k = 0; k < DD / 4; k += 2) {
                float4 w0 = wp[k], w1 = wp[k + 1];
                float4 u0 = xp[k], u1 = xp[k + 1];
                a0 += w0.x * u0.x + w0.y * u0.y + w0.z * u0.z + w0.w * u0.w;
                a1 += w1.x * u1.x + w1.y * u1.y + w1.z * u1.z + w1.w * u1.w;
            }
            float h0 = a0 + a1 + l1b[c];
            xs0[m][c] = (h0 >= 0.f) ? h0 : 0.01f * h0;
        }
    }
    __syncthreads();

    // nonlin ownership: lane holds 2 batch rows (mA, mA+1) for hidden ic
    const int mA  = (lane < 32) ? 4 * lq : 4 * (lq - 2) + 2;
    const int iN  = ic;
    const int rB_ = 16 * ((iN >> 3) & 3);
    const int cB_ = 8 * (iN >> 5) + (iN & 7);

    float hA = 0.f, hB = 0.f;
    int  len   = TT;
    bool found = false;
    int  tex   = TT;

    // chars(t-1): M-packed MFMA from l2v[slot]; split issue/commit
    auto chars_mfma = [&](int slot, f32x4& c0, f32x4& c1) {
        #pragma unroll
        for (int kt = 0; kt < 4; ++kt) {
            f16x8 cf  = *(const f16x8*)&l2v[slot][lane][8 * kt];
            f16x8 wl0 = *(const f16x8*)&bclS[2 * cw + 0][kt][lq][lm][0];
            f16x8 wl1 = *(const f16x8*)&bclS[2 * cw + 1][kt][lq][lm][0];
            c0 = __builtin_amdgcn_mfma_f32_16x16x32_f16(cf, bch[0][kt], c0, 0, 0, 0);
            c0 = __builtin_amdgcn_mfma_f32_16x16x32_f16(cf, wl0,        c0, 0, 0, 0);
            c1 = __builtin_amdgcn_mfma_f32_16x16x32_f16(cf, bch[1][kt], c1, 0, 0, 0);
            c1 = __builtin_amdgcn_mfma_f32_16x16x32_f16(cf, wl1,        c1, 0, 0, 0);
        }
    };
    auto chars_commit = [&](int slot, f32x4 c0, f32x4 c1) {
        #pragma unroll
        for (int u = 0; u < 2; ++u) {
            f32x4 ca = u ? c1 : c0;
            const int n = 16 * (2 * cw + u) + lm;
            float s0 = xsum32(ca[0]);
            float s1 = xsum32(ca[1]);
            float s2 = xsum32(ca[2]);
            float s3 = xsum32(ca[3]);
            chs[slot][mA][n]     = ((lane < 32) ? s0 : s2) + cb[u];
            chs[slot][mA + 1][n] = ((lane < 32) ? s1 : s3) + cb[u];
        }
    };

    // full-row normalized write of chars at time tme from chs[slot]; wave w = row
    // 96 values as 3/lane in lanes<32; width-32 reduce (max3 + 5 swizzles)
    auto outrow = [&](int slot, int tme) {
        const float* cr = &chs[slot][w][0];
        float a0 = cr[lane];
        float a1 = cr[32 + lane];
        float a2 = cr[64 + lane];
        float mx = fmaxf(fmaxf(a0, a1), a2);
        mx = fmaxf(mx, __shfl_xor(mx, 16, 32));
        mx = fmaxf(mx, __shfl_xor(mx, 8, 32));
        mx = fmaxf(mx, __shfl_xor(mx, 4, 32));
        mx = fmaxf(mx, __shfl_xor(mx, 2, 32));
        mx = fmaxf(mx, __shfl_xor(mx, 1, 32));
        float q0 = a0 / mx;   // exact IEEE divide: q52 == 1.0f check + stored
        float q1 = a1 / mx;   // values must match reference bitwise
        float q2 = a2 / mx;
        if (lane < 32) {
            size_t base = ((size_t)(b0 + w) * TT + tme) * CC;
            out[base + lane]      = (q0 > THRV) ? q0 : 0.f;
            out[base + 32 + lane] = (q1 > THRV) ? q1 : 0.f;
            out[base + 64 + lane] = (q2 > THRV) ? q2 : 0.f;
        }
        float q52 = __shfl(q1, 20, 64);   // element 52 = 32 + 20
        if (!found && q52 == 1.0f) { found = true; len = tme + 1; }
    };

    for (int t = 0; t < TT; ++t) {
        const int pr = (t + 1) & 1;   // read slot  ((t-1)&1)
        const int pc = t & 1;         // write slot; == (t-2)&1 for chs

        float G[4][2];

        if (t == 0) {
            // exact-f32 gates from xs0 (wih only for g<3; h=0 -> g=3 is bias only)
            {
                const int g = tid >> 7;        // 0..3
                const int i = tid & 127;
                float bsum;
                if (g == 0)      bsum = bih[i] + bhh[i];
                else if (g == 1) bsum = bih[128 + i] + bhh[128 + i];
                else if (g == 2) bsum = bih[256 + i];
                else             bsum = bhh[256 + i];
                float accT[NB];
                #pragma unroll
                for (int m = 0; m < NB; ++m) accT[m] = bsum;
                if (g < 3) {
                    const float4* wp = (const float4*)(wih + (size_t)(128 * g + i) * HH);
                    #pragma unroll
                    for (int k = 0; k < HH / 4; ++k) {
                        float4 wv = wp[k];
                        #pragma unroll
                        for (int m = 0; m < NB; ++m) {
                            float4 x = *(const float4*)&xs0[m][4 * k];
                            accT[m] += wv.x * x.x + wv.y * x.y + wv.z * x.z + wv.w * x.w;
                        }
                    }
                }
                float4 lo4 = {accT[0], accT[1], accT[2], accT[3]};
                float4 hi4 = {accT[4], accT[5], accT[6], accT[7]};
                *(float4*)&gsT[g][i][0] = lo4;
                *(float4*)&gsT[g][i][4] = hi4;
            }
            step_barrier();
            #pragma unroll
            for (int g = 0; g < 4; ++g) {
                float2 p = *(const float2*)&gsT[g][iN][mA];
                G[g][0] = p.x;
                G[g][1] = p.y;
            }
        } else {
            // ---- 1. gates(t) FIRST: A-frag loads + MFMA issue, 2 accs/gate ----
            f16x8 af0 = *(const f16x8*)&x2[pr][lane][0];
            f16x8 af1 = *(const f16x8*)&x2[pr][lane][8];
            f16x8 af2 = *(const f16x8*)&x2[pr][lane][16];
            f16x8 af3 = *(const f16x8*)&x2[pr][lane][24];
            f32x4 z4 = {0.f, 0.f, 0.f, 0.f};
            f32x4 aA[4] = {z4, z4, z4, z4};
            f32x4 aB[4] = {z4, z4, z4, z4};
            #pragma unroll
            for (int g = 0; g < 4; ++g) {
                aA[g] = __builtin_amdgcn_mfma_f32_16x16x32_f16(af0, bh[g][0], aA[g], 0, 0, 0);
                aA[g] = __builtin_amdgcn_mfma_f32_16x16x32_f16(af0, bl[g][0], aA[g], 0, 0, 0);
                aA[g] = __builtin_amdgcn_mfma_f32_16x16x32_f16(af1, bh[g][1], aA[g], 0, 0, 0);
                aA[g] = __builtin_amdgcn_mfma_f32_16x16x32_f16(af1, bl[g][1], aA[g], 0, 0, 0);
                aB[g] = __builtin_amdgcn_mfma_f32_16x16x32_f16(af2, bh[g][2], aB[g], 0, 0, 0);
                aB[g] = __builtin_amdgcn_mfma_f32_16x16x32_f16(af2, bl[g][2], aB[g], 0, 0, 0);
                aB[g] = __builtin_amdgcn_mfma_f32_16x16x32_f16(af3, bh[g][3], aB[g], 0, 0, 0);
                aB[g] = __builtin_amdgcn_mfma_f32_16x16x32_f16(af3, bl[g][3], aB[g], 0, 0, 0);
            }
            // ---- 2. chars(t-1) MFMA under the gate-MFMA shadow ----
            f32x4 cc0 = z4, cc1 = z4;
            if (cw >= 0) chars_mfma(pr, cc0, cc1);
            // ---- 3. OUTROW(t-2): LDS/shuffle chain overlaps MFMA pipe ----
            if (t >= 2) outrow(pc, t - 2);
            // ---- 4. gate combine (hi rows 0-7 + lo rows 8-15) + bias ----
            #pragma unroll
            for (int g = 0; g < 4; ++g) {
                f32x4 s4 = aA[g] + aB[g];
                float s0 = xsum32(s4[0]);
                float s1 = xsum32(s4[1]);
                float s2 = xsum32(s4[2]);
                float s3 = xsum32(s4[3]);
                G[g][0] = ((lane < 32) ? s0 : s2) + gb[g];
                G[g][1] = ((lane < 32) ? s1 : s3) + gb[g];
            }
            // ---- 5. chars commit ----
            if (cw >= 0) chars_commit(pr, cc0, cc1);
        }

        // ---- GRU nonlinearity, fully in-lane, 2 rows/lane ----
        bool chg = (t < 2);
        #pragma unroll
        for (int s = 0; s < 2; ++s) {
            float hp = s ? hB : hA;
            float r  = sigm(G[0][s]);
            float z  = sigm(G[1][s]);
            float n  = ftanh(G[2][s] + r * G[3][s]);
            float h  = (1.f - z) * n + z * hp;
            chg |= (fabsf(h - hp) > HEPS);
            float lv = (h >= 0.f) ? h : 0.01f * h;
            _Float16 a, b;
            split1(h, a, b);
            x2[pc][rB_ + mA + s][cB_]     = a;
            x2[pc][rB_ + 8 + mA + s][cB_] = b;
            split1(lv, a, b);
            l2v[pc][rB_ + mA + s][cB_]     = a;
            l2v[pc][rB_ + 8 + mA + s][cB_] = b;
            if (s) hB = h; else hA = h;
        }
        if (chg) sh_st[t & 3] = 0;              // benign multi-writer race
        if (tid == 0) sh_st[(t + 2) & 3] = 1;   // slot for t+2; 2 barriers from its writers
        step_barrier();                         // NO vmcnt drain: stores stay in flight
        if (t >= 2 && sh_st[t & 3]) { tex = t; break; }
    }

    if (tex == TT) {
        // natural end: write chars(TT-2); compute + write chars(TT-1)
        const int pl = (TT - 1) & 1;
        if (cw >= 0) {
            f32x4 z4 = {0.f, 0.f, 0.f, 0.f};
            f32x4 cc0 = z4, cc1 = z4;
            chars_mfma(pl, cc0, cc1);
            chars_commit(pl, cc0, cc1);
        }
        outrow(TT & 1, TT - 2);
        __syncthreads();
        outrow(pl, TT - 1);
    } else {
        // frozen from tex: loop wrote times 0..tex-2. Write chars(tex-1), then
        // fill [tex, TT) with the two parity patterns (zeros included), stride-2.
        outrow((tex + 1) & 1, tex - 1);
        size_t rowbase = (size_t)(b0 + w) * TT * CC;
        #pragma unroll
        for (int p = 0; p < 2; ++p) {
            const float* cr = &chs[p][w][0];
            float a0 = cr[lane];
            float a1 = cr[32 + lane];
            float a2 = cr[64 + lane];
            float mx = fmaxf(fmaxf(a0, a1), a2);
            mx = fmaxf(mx, __shfl_xor(mx, 16, 32));
            mx = fmaxf(mx, __shfl_xor(mx, 8, 32));
            mx = fmaxf(mx, __shfl_xor(mx, 4, 32));
            mx = fmaxf(mx, __shfl_xor(mx, 2, 32));
            mx = fmaxf(mx, __shfl_xor(mx, 1, 32));
            const int u0 = tex + (((tex & 1) == p) ? 0 : 1);
            if (lane < 32) {
                float q0 = a0 / mx;
                float q1 = a1 / mx;
                float q2 = a2 / mx;
                float w0v = (q0 > THRV) ? q0 : 0.f;
                float w1v = (q1 > THRV) ? q1 : 0.f;
                float w2v = (q2 > THRV) ? q2 : 0.f;
                for (int u = u0; u < TT; u += 2) {
                    out[rowbase + (size_t)u * CC + lane]      = w0v;
                    out[rowbase + (size_t)u * CC + 32 + lane] = w1v;
                    out[rowbase + (size_t)u * CC + 64 + lane] = w2v;
                }
            }
        }
        // lens: frozen pattern's char-52 hit (if any) recorded at tex-2 / tex-1.
    }

    if (lane == 0) lens[b0 + w] = (float)len;
}

extern "C" void kernel_launch(void* const* d_in, const int* in_sizes, int n_in,
                              void* d_out, int out_size, void* d_ws, size_t ws_size,
                              hipStream_t stream)
{
    const float* img = (const float*)d_in[0];
    const float* l1w = (const float*)d_in[1];
    const float* l1b = (const float*)d_in[2];
    const float* wih = (const float*)d_in[3];
    const float* whh = (const float*)d_in[4];
    const float* bih = (const float*)d_in[5];
    const float* bhh = (const float*)d_in[6];
    const float* l2w = (const float*)d_in[7];
    const float* l2b = (const float*)d_in[8];

    float* out  = (float*)d_out;
    float* lens = out + (size_t)2048 * TT * CC;

    // no memset: the kernel writes every title element exactly once
    // (full-row coalesced stores with explicit zeros) and all lens entries.
    gru_title<<<dim3(2048 / NB), dim3(512), 0, stream>>>(
        img, l1w, l1b, wih, whh, bih, bhh, l2w, l2b, out, lens);
}

// Round 4
// 651.725 us; speedup vs baseline: 1.7357x; 1.7179x over previous
//
#include <hip/hip_runtime.h>
#include <math.h>

#define NB   8
#define TT   400
#define HH   128
#define CC   96
#define DD   4096
#define THRV (1.0f - 1e-5f)
#define XR   40      // f16 row pad: 80 B rows (5*16B -> b128-aligned, clean bank walk)
#define HEPS 4e-6f   // convergence tolerance (same class-proven margin as before)
#define CHP  128     // chs row stride (padded so lanes>=32 reads stay in-row)
#define S10  1024.0f            // lo-split scale (keeps lo out of f16 subnormals)
#define IS10 0.0009765625f      // 2^-10
#define IS20 9.5367431640625e-07f  // 2^-20

typedef _Float16 f16x8 __attribute__((ext_vector_type(8)));
typedef float    f32x4 __attribute__((ext_vector_type(4)));

__device__ __forceinline__ float rcp_fast(float x) {
#if __has_builtin(__builtin_amdgcn_rcpf)
    return __builtin_amdgcn_rcpf(x);
#else
    return 1.0f / x;
#endif
}
// v_exp_f32-based sigmoid/tanh: ~1e-7 err, far inside the proven 5e-5 margin.
__device__ __forceinline__ float sigm(float v)  { return rcp_fast(1.0f + __expf(-v)); }
__device__ __forceinline__ float ftanh(float x) { return 1.0f - 2.0f * rcp_fast(1.0f + __expf(2.0f * x)); }

__device__ __forceinline__ void split2(float4 u0, float4 u1, f16x8& hi, f16x8& lo) {
    float x[8] = {u0.x, u0.y, u0.z, u0.w, u1.x, u1.y, u1.z, u1.w};
    #pragma unroll
    for (int e = 0; e < 8; ++e) {
        _Float16 h = (_Float16)x[e];
        hi[e] = h;
        lo[e] = (_Float16)(x[e] - (float)h);
    }
}
// scaled variant: lo is stored *1024 so residuals stay in f16 normal range
__device__ __forceinline__ void split2s(float4 u0, float4 u1, f16x8& hi, f16x8& lo) {
    float x[8] = {u0.x, u0.y, u0.z, u0.w, u1.x, u1.y, u1.z, u1.w};
    #pragma unroll
    for (int e = 0; e < 8; ++e) {
        _Float16 h = (_Float16)x[e];
        hi[e] = h;
        lo[e] = (_Float16)((x[e] - (float)h) * S10);
    }
}
__device__ __forceinline__ void split1(float x, _Float16& hi, _Float16& lo) {
    hi = (_Float16)x;
    lo = (_Float16)(x - (float)hi);
}

// lane ^ 32 combine on the VALU pipe (keeps the LDS pipe free)
__device__ __forceinline__ float xsum32(float v) {
#if __has_builtin(__builtin_amdgcn_permlane32_swap)
    auto r = __builtin_amdgcn_permlane32_swap(__float_as_uint(v), __float_as_uint(v), false, false);
    return __uint_as_float(r[0]) + __uint_as_float(r[1]);
#else
    return v + __shfl_xor(v, 32, 64);
#endif
}

// Barrier WITHOUT the vmcnt(0) drain __syncthreads would emit: global stores
// (out[]) are fire-and-forget (nothing reads them), so only LDS ops need to
// complete before waves cross.
__device__ __forceinline__ void step_barrier() {
    __builtin_amdgcn_sched_barrier(0);
    asm volatile("s_waitcnt lgkmcnt(0)" ::: "memory");
    __builtin_amdgcn_s_barrier();
    asm volatile("" ::: "memory");
    __builtin_amdgcn_sched_barrier(0);
}

__global__ __launch_bounds__(512)
void gru_title(const float* __restrict__ img,
               const float* __restrict__ l1w,
               const float* __restrict__ l1b,
               const float* __restrict__ wih,
               const float* __restrict__ whh,
               const float* __restrict__ bih,
               const float* __restrict__ bhh,
               const float* __restrict__ l2w,
               const float* __restrict__ l2b,
               float* __restrict__ out,
               float* __restrict__ lens)
{
    // M-packed A layout: value (m, k, hi) at row 16*((k>>3)&3)+m, (lo) at +8;
    // f16 col 8*(k>>5)+(k&7).  A-frag read is then simply row=lane, col=8*kt.
    __shared__ alignas(16) _Float16 x2 [2][64][XR];   // h   hi rows 0-7, lo rows 8-15 per 16-group
    __shared__ alignas(16) _Float16 l2v[2][64][XR];   // leaky(h), same layout
    __shared__ alignas(16) float    chs[2][NB][CHP];  // chars, parity-buffered, padded rows
    __shared__ alignas(16) _Float16 bclS[6][4][4][16][8]; // chars lo-weights (24 KB)
    __shared__ alignas(16) float    gsT[4][HH][NB];   // t=0 scalar gate staging
    __shared__ alignas(16) float    xs0[NB][HH];      // x0 (t=0 scalar path)
    __shared__ int sh_st[4];                          // stable flags, 4-slot rotation

    const int tid  = threadIdx.x;
    const int b0   = blockIdx.x * NB;
    const int w    = tid >> 6;     // wave 0..7
    const int lane = tid & 63;
    const int lm   = lane & 15;
    const int lq   = lane >> 4;

    // ---- gate weights: wave w owns ALL 4 gate types for i-chunk [16w,16w+16) ----
    // g=0: r (wih+whh fused, x==h for t>=1); g=1: z (fused); g=2: n_i (wih); g=3: n_h (whh)
    f16x8 bh[4][4], bl[4][4];
    float gb[4];
    const int ic = 16 * w + lm;    // hidden col this lane owns
    #pragma unroll
    for (int g = 0; g < 4; ++g) {
        const float* r0;
        const float* r1 = nullptr;
        float bsum;
        if (g == 0)      { r0 = wih + (size_t)ic * HH;         r1 = whh + (size_t)ic * HH;         bsum = bih[ic] + bhh[ic]; }
        else if (g == 1) { r0 = wih + (size_t)(128 + ic) * HH; r1 = whh + (size_t)(128 + ic) * HH; bsum = bih[128 + ic] + bhh[128 + ic]; }
        else if (g == 2) { r0 = wih + (size_t)(256 + ic) * HH;                                     bsum = bih[256 + ic]; }
        else             { r0 = whh + (size_t)(256 + ic) * HH;                                     bsum = bhh[256 + ic]; }
        gb[g] = bsum;
        #pragma unroll
        for (int kt = 0; kt < 4; ++kt) {
            const int k0 = 32 * kt + 8 * lq;
            float4 u0 = *(const float4*)(r0 + k0);
            float4 u1 = *(const float4*)(r0 + k0 + 4);
            if (r1) {
                float4 e0 = *(const float4*)(r1 + k0);
                float4 e1 = *(const float4*)(r1 + k0 + 4);
                u0.x += e0.x; u0.y += e0.y; u0.z += e0.z; u0.w += e0.w;
                u1.x += e1.x; u1.y += e1.y; u1.z += e1.z; u1.w += e1.w;
            }
            split2(u0, u1, bh[g][kt], bl[g][kt]);
        }
    }

    // ---- chars: waves 1,3,6 (distinct SIMDs) own 2 col-tiles each ----
    const int cw = (w == 1) ? 0 : (w == 3) ? 1 : (w == 6) ? 2 : -1;
    f16x8 bch[2][4];
    float cb[2] = {0.f, 0.f};
    if (cw >= 0) {
        #pragma unroll
        for (int u = 0; u < 2; ++u) {
            const int n = 16 * (2 * cw + u) + lm;
            cb[u] = l2b[n];
            #pragma unroll
            for (int kt = 0; kt < 4; ++kt) {
                const int k0 = 32 * kt + 8 * lq;
                float4 u0 = *(const float4*)(l2w + (size_t)n * HH + k0);
                float4 u1 = *(const float4*)(l2w + (size_t)n * HH + k0 + 4);
                f16x8 hi, lo;
                split2(u0, u1, hi, lo);
                bch[u][kt] = hi;
            }
        }
    }
    // stash chars lo-weights in LDS (all threads help)
    for (int idx = tid; idx < 6 * 4 * 4 * 16; idx += 512) {
        int t_  = idx;
        int lm_ = t_ & 15; t_ >>= 4;
        int lq_ = t_ & 3;  t_ >>= 2;
        int kt_ = t_ & 3;  t_ >>= 2;
        int ct_ = t_;                       // 0..5
        const int n  = 16 * ct_ + lm_;
        const int k0 = 32 * kt_ + 8 * lq_;
        #pragma unroll
        for (int e = 0; e < 8; ++e) {
            float v = l2w[(size_t)n * HH + k0 + e];
            _Float16 hi = (_Float16)v;
            bclS[ct_][kt_][lq_][lm_][e] = (_Float16)(v - (float)hi);
        }
    }

    if (tid < 4) sh_st[tid] = 1;

    // ---- prologue: x0 = leaky(img @ l1w.T + l1b) via hi/lo f16 MFMA GEMM ----
    // Wave w owns output cols c = 16w + lm. A = img rows M-packed: rows 0-7 hi,
    // rows 8-15 lo*2^10. B = l1w col rows, hi + lo*2^10. Two MFMAs per 32-k
    // tile produce all four hi/lo cross terms; per-lane-group descale after.
    {
        const int m8 = lm & 7;
        const float* arow = img + (size_t)(b0 + m8) * DD + 8 * lq;
        const float* brow = l1w + (size_t)(16 * w + lm) * DD + 8 * lq;
        f32x4 z4 = {0.f, 0.f, 0.f, 0.f};
        f32x4 accP0 = z4, accP1 = z4, accQ0 = z4, accQ1 = z4;
        auto ptile = [&](int kt, f32x4& aP, f32x4& aQ) {
            float4 a0  = *(const float4*)(arow + 32 * kt);
            float4 a1  = *(const float4*)(arow + 32 * kt + 4);
            float4 bb0 = *(const float4*)(brow + 32 * kt);
            float4 bb1 = *(const float4*)(brow + 32 * kt + 4);
            f16x8 ah, al, bhf, blf;
            split2s(a0, a1, ah, al);
            split2s(bb0, bb1, bhf, blf);
            f16x8 af = (lm >= 8) ? al : ah;   // lanes lm>=8 carry scaled-lo rows
            aP = __builtin_amdgcn_mfma_f32_16x16x32_f16(af, bhf, aP, 0, 0, 0);
            aQ = __builtin_amdgcn_mfma_f32_16x16x32_f16(af, blf, aQ, 0, 0, 0);
        };
        #pragma unroll 2
        for (int kt = 0; kt < DD / 32; kt += 2) {
            ptile(kt,     accP0, accQ0);
            ptile(kt + 1, accP1, accQ1);
        }
        f32x4 P = accP0 + accP1;
        f32x4 Q = accQ0 + accQ1;
        // lanes<32 hold hi-rows: total = P + Q*2^-10
        // lanes>=32 hold lo*2^10 rows: total = P*2^-10 + Q*2^-20
        const float sP = (lane < 32) ? 1.0f  : IS10;
        const float sQ = (lane < 32) ? IS10 : IS20;
        float s0 = xsum32(P[0] * sP + Q[0] * sQ);
        float s1 = xsum32(P[1] * sP + Q[1] * sQ);
        float s2 = xsum32(P[2] * sP + Q[2] * sQ);
        float s3 = xsum32(P[3] * sP + Q[3] * sQ);
        if (lane < 32) {     // lq in {0,1}: rows 4lq+reg cover m=0..7
            const int c = 16 * w + lm;
            const float bb = l1b[c];
            float vv[4] = {s0, s1, s2, s3};
            #pragma unroll
            for (int reg = 0; reg < 4; ++reg) {
                float h0 = vv[reg] + bb;
                xs0[4 * lq + reg][c] = (h0 >= 0.f) ? h0 : 0.01f * h0;
            }
        }
    }
    __syncthreads();

    // nonlin ownership: lane holds 2 batch rows (mA, mA+1) for hidden ic
    const int mA  = (lane < 32) ? 4 * lq : 4 * (lq - 2) + 2;
    const int iN  = ic;
    const int rB_ = 16 * ((iN >> 3) & 3);
    const int cB_ = 8 * (iN >> 5) + (iN & 7);

    float hA = 0.f, hB = 0.f;
    int  len   = TT;
    bool found = false;
    int  tex   = TT;

    // chars(t-1): M-packed MFMA from l2v[slot]; split issue/commit
    auto chars_mfma = [&](int slot, f32x4& c0, f32x4& c1) {
        #pragma unroll
        for (int kt = 0; kt < 4; ++kt) {
            f16x8 cf  = *(const f16x8*)&l2v[slot][lane][8 * kt];
            f16x8 wl0 = *(const f16x8*)&bclS[2 * cw + 0][kt][lq][lm][0];
            f16x8 wl1 = *(const f16x8*)&bclS[2 * cw + 1][kt][lq][lm][0];
            c0 = __builtin_amdgcn_mfma_f32_16x16x32_f16(cf, bch[0][kt], c0, 0, 0, 0);
            c0 = __builtin_amdgcn_mfma_f32_16x16x32_f16(cf, wl0,        c0, 0, 0, 0);
            c1 = __builtin_amdgcn_mfma_f32_16x16x32_f16(cf, bch[1][kt], c1, 0, 0, 0);
            c1 = __builtin_amdgcn_mfma_f32_16x16x32_f16(cf, wl1,        c1, 0, 0, 0);
        }
    };
    auto chars_commit = [&](int slot, f32x4 c0, f32x4 c1) {
        #pragma unroll
        for (int u = 0; u < 2; ++u) {
            f32x4 ca = u ? c1 : c0;
            const int n = 16 * (2 * cw + u) + lm;
            float s0 = xsum32(ca[0]);
            float s1 = xsum32(ca[1]);
            float s2 = xsum32(ca[2]);
            float s3 = xsum32(ca[3]);
            chs[slot][mA][n]     = ((lane < 32) ? s0 : s2) + cb[u];
            chs[slot][mA + 1][n] = ((lane < 32) ? s1 : s3) + cb[u];
        }
    };

    // full-row normalized write of chars at time tme from chs[slot]; wave w = row
    auto outrow = [&](int slot, int tme) {
        const float* cr = &chs[slot][w][0];
        float a0 = cr[lane];
        float a1 = cr[32 + lane];
        float a2 = cr[64 + lane];
        float mx = fmaxf(fmaxf(a0, a1), a2);
        mx = fmaxf(mx, __shfl_xor(mx, 16, 32));
        mx = fmaxf(mx, __shfl_xor(mx, 8, 32));
        mx = fmaxf(mx, __shfl_xor(mx, 4, 32));
        mx = fmaxf(mx, __shfl_xor(mx, 2, 32));
        mx = fmaxf(mx, __shfl_xor(mx, 1, 32));
        float q0 = a0 / mx;   // exact IEEE divide: q52 == 1.0f check + stored
        float q1 = a1 / mx;   // values must match reference bitwise
        float q2 = a2 / mx;
        if (lane < 32) {
            size_t base = ((size_t)(b0 + w) * TT + tme) * CC;
            out[base + lane]      = (q0 > THRV) ? q0 : 0.f;
            out[base + 32 + lane] = (q1 > THRV) ? q1 : 0.f;
            out[base + 64 + lane] = (q2 > THRV) ? q2 : 0.f;
        }
        float q52 = __shfl(q1, 20, 64);   // element 52 = 32 + 20
        if (!found && q52 == 1.0f) { found = true; len = tme + 1; }
    };

    for (int t = 0; t < TT; ++t) {
        const int pr = (t + 1) & 1;   // read slot  ((t-1)&1)
        const int pc = t & 1;         // write slot; == (t-2)&1 for chs

        float G[4][2];

        if (t == 0) {
            // exact-f32 gates from xs0 (wih only for g<3; h=0 -> g=3 is bias only)
            {
                const int g = tid >> 7;        // 0..3
                const int i = tid & 127;
                float bsum;
                if (g == 0)      bsum = bih[i] + bhh[i];
                else if (g == 1) bsum = bih[128 + i] + bhh[128 + i];
                else if (g == 2) bsum = bih[256 + i];
                else             bsum = bhh[256 + i];
                float accT[NB];
                #pragma unroll
                for (int m = 0; m < NB; ++m) accT[m] = bsum;
                if (g < 3) {
                    const float4* wp = (const float4*)(wih + (size_t)(128 * g + i) * HH);
                    #pragma unroll
                    for (int k = 0; k < HH / 4; ++k) {
                        float4 wv = wp[k];
                        #pragma unroll
                        for (int m = 0; m < NB; ++m) {
                            float4 x = *(const float4*)&xs0[m][4 * k];
                            accT[m] += wv.x * x.x + wv.y * x.y + wv.z * x.z + wv.w * x.w;
                        }
                    }
                }
                float4 lo4 = {accT[0], accT[1], accT[2], accT[3]};
                float4 hi4 = {accT[4], accT[5], accT[6], accT[7]};
                *(float4*)&gsT[g][i][0] = lo4;
                *(float4*)&gsT[g][i][4] = hi4;
            }
            step_barrier();
            #pragma unroll
            for (int g = 0; g < 4; ++g) {
                float2 p = *(const float2*)&gsT[g][iN][mA];
                G[g][0] = p.x;
                G[g][1] = p.y;
            }
        } else {
            // ---- 1. gates(t) FIRST: A-frag loads + MFMA issue, 2 accs/gate ----
            f16x8 af0 = *(const f16x8*)&x2[pr][lane][0];
            f16x8 af1 = *(const f16x8*)&x2[pr][lane][8];
            f16x8 af2 = *(const f16x8*)&x2[pr][lane][16];
            f16x8 af3 = *(const f16x8*)&x2[pr][lane][24];
            f32x4 z4 = {0.f, 0.f, 0.f, 0.f};
            f32x4 aA[4] = {z4, z4, z4, z4};
            f32x4 aB[4] = {z4, z4, z4, z4};
            #pragma unroll
            for (int g = 0; g < 4; ++g) {
                aA[g] = __builtin_amdgcn_mfma_f32_16x16x32_f16(af0, bh[g][0], aA[g], 0, 0, 0);
                aA[g] = __builtin_amdgcn_mfma_f32_16x16x32_f16(af0, bl[g][0], aA[g], 0, 0, 0);
                aA[g] = __builtin_amdgcn_mfma_f32_16x16x32_f16(af1, bh[g][1], aA[g], 0, 0, 0);
                aA[g] = __builtin_amdgcn_mfma_f32_16x16x32_f16(af1, bl[g][1], aA[g], 0, 0, 0);
                aB[g] = __builtin_amdgcn_mfma_f32_16x16x32_f16(af2, bh[g][2], aB[g], 0, 0, 0);
                aB[g] = __builtin_amdgcn_mfma_f32_16x16x32_f16(af2, bl[g][2], aB[g], 0, 0, 0);
                aB[g] = __builtin_amdgcn_mfma_f32_16x16x32_f16(af3, bh[g][3], aB[g], 0, 0, 0);
                aB[g] = __builtin_amdgcn_mfma_f32_16x16x32_f16(af3, bl[g][3], aB[g], 0, 0, 0);
            }
            // ---- 2. chars(t-1) MFMA under the gate-MFMA shadow ----
            f32x4 cc0 = z4, cc1 = z4;
            if (cw >= 0) chars_mfma(pr, cc0, cc1);
            // ---- 3. OUTROW(t-2): LDS/shuffle chain overlaps MFMA pipe ----
            if (t >= 2) outrow(pc, t - 2);
            // ---- 4. gate combine (hi rows 0-7 + lo rows 8-15) + bias ----
            #pragma unroll
            for (int g = 0; g < 4; ++g) {
                f32x4 s4 = aA[g] + aB[g];
                float s0 = xsum32(s4[0]);
                float s1 = xsum32(s4[1]);
                float s2 = xsum32(s4[2]);
                float s3 = xsum32(s4[3]);
                G[g][0] = ((lane < 32) ? s0 : s2) + gb[g];
                G[g][1] = ((lane < 32) ? s1 : s3) + gb[g];
            }
            // ---- 5. chars commit ----
            if (cw >= 0) chars_commit(pr, cc0, cc1);
        }

        // ---- GRU nonlinearity, fully in-lane, 2 rows/lane ----
        bool chg = (t < 2);
        #pragma unroll
        for (int s = 0; s < 2; ++s) {
            float hp = s ? hB : hA;
            float r  = sigm(G[0][s]);
            float z  = sigm(G[1][s]);
            float n  = ftanh(G[2][s] + r * G[3][s]);
            float h  = (1.f - z) * n + z * hp;
            chg |= (fabsf(h - hp) > HEPS);
            float lv = (h >= 0.f) ? h : 0.01f * h;
            _Float16 a, b;
            split1(h, a, b);
            x2[pc][rB_ + mA + s][cB_]     = a;
            x2[pc][rB_ + 8 + mA + s][cB_] = b;
            split1(lv, a, b);
            l2v[pc][rB_ + mA + s][cB_]     = a;
            l2v[pc][rB_ + 8 + mA + s][cB_] = b;
            if (s) hB = h; else hA = h;
        }
        if (chg) sh_st[t & 3] = 0;              // benign multi-writer race
        if (tid == 0) sh_st[(t + 2) & 3] = 1;   // slot for t+2; 2 barriers from its writers
        step_barrier();                         // NO vmcnt drain: stores stay in flight
        if (t >= 2 && sh_st[t & 3]) { tex = t; break; }
    }

    if (tex == TT) {
        // natural end: write chars(TT-2); compute + write chars(TT-1)
        const int pl = (TT - 1) & 1;
        if (cw >= 0) {
            f32x4 z4 = {0.f, 0.f, 0.f, 0.f};
            f32x4 cc0 = z4, cc1 = z4;
            chars_mfma(pl, cc0, cc1);
            chars_commit(pl, cc0, cc1);
        }
        outrow(TT & 1, TT - 2);
        __syncthreads();
        outrow(pl, TT - 1);
    } else {
        // frozen from tex: loop wrote times 0..tex-2. Write chars(tex-1), then
        // fill [tex, TT) with the two parity patterns (zeros included), stride-2.
        outrow((tex + 1) & 1, tex - 1);
        size_t rowbase = (size_t)(b0 + w) * TT * CC;
        #pragma unroll
        for (int p = 0; p < 2; ++p) {
            const float* cr = &chs[p][w][0];
            float a0 = cr[lane];
            float a1 = cr[32 + lane];
            float a2 = cr[64 + lane];
            float mx = fmaxf(fmaxf(a0, a1), a2);
            mx = fmaxf(mx, __shfl_xor(mx, 16, 32));
            mx = fmaxf(mx, __shfl_xor(mx, 8, 32));
            mx = fmaxf(mx, __shfl_xor(mx, 4, 32));
            mx = fmaxf(mx, __shfl_xor(mx, 2, 32));
            mx = fmaxf(mx, __shfl_xor(mx, 1, 32));
            const int u0 = tex + (((tex & 1) == p) ? 0 : 1);
            if (lane < 32) {
                float q0 = a0 / mx;
                float q1 = a1 / mx;
                float q2 = a2 / mx;
                float w0v = (q0 > THRV) ? q0 : 0.f;
                float w1v = (q1 > THRV) ? q1 : 0.f;
                float w2v = (q2 > THRV) ? q2 : 0.f;
                for (int u = u0; u < TT; u += 2) {
                    out[rowbase + (size_t)u * CC + lane]      = w0v;
                    out[rowbase + (size_t)u * CC + 32 + lane] = w1v;
                    out[rowbase + (size_t)u * CC + 64 + lane] = w2v;
                }
            }
        }
        // lens: frozen pattern's char-52 hit (if any) recorded at tex-2 / tex-1.
    }

    if (lane == 0) lens[b0 + w] = (float)len;
}

extern "C" void kernel_launch(void* const* d_in, const int* in_sizes, int n_in,
                              void* d_out, int out_size, void* d_ws, size_t ws_size,
                              hipStream_t stream)
{
    const float* img = (const float*)d_in[0];
    const float* l1w = (const float*)d_in[1];
    const float* l1b = (const float*)d_in[2];
    const float* wih = (const float*)d_in[3];
    const float* whh = (const float*)d_in[4];
    const float* bih = (const float*)d_in[5];
    const float* bhh = (const float*)d_in[6];
    const float* l2w = (const float*)d_in[7];
    const float* l2b = (const float*)d_in[8];

    float* out  = (float*)d_out;
    float* lens = out + (size_t)2048 * TT * CC;

    // no memset: the kernel writes every title element exactly once
    // (full-row coalesced stores with explicit zeros) and all lens entries.
    gru_title<<<dim3(2048 / NB), dim3(512), 0, stream>>>(
        img, l1w, l1b, wih, whh, bih, bhh, l2w, l2b, out, lens);
}

// Round 5
// 633.608 us; speedup vs baseline: 1.7853x; 1.0286x over previous
//
#include <hip/hip_runtime.h>
#include <math.h>

#define NB   8
#define TT   400
#define HH   128
#define CC   96
#define DD   4096
#define THRV (1.0f - 1e-5f)
#define XR   40      // f16 row pad: 80 B rows (5*16B -> b128-aligned, clean bank walk)
#define HEPS 4e-6f   // convergence tolerance (same class-proven margin as before)
#define S10  1024.0f            // lo-split scale (keeps lo out of f16 subnormals)
#define IS10 0.0009765625f      // 2^-10
#define IS20 9.5367431640625e-07f  // 2^-20

typedef _Float16 f16x8 __attribute__((ext_vector_type(8)));
typedef float    f32x4 __attribute__((ext_vector_type(4)));
typedef float    f32x2 __attribute__((ext_vector_type(2)));

__device__ __forceinline__ float rcp_fast(float x) {
#if __has_builtin(__builtin_amdgcn_rcpf)
    return __builtin_amdgcn_rcpf(x);
#else
    return 1.0f / x;
#endif
}
// v_exp_f32-based sigmoid/tanh: ~1e-7 err, far inside the proven 5e-5 margin.
__device__ __forceinline__ float sigm(float v)  { return rcp_fast(1.0f + __expf(-v)); }
__device__ __forceinline__ float ftanh(float x) { return 1.0f - 2.0f * rcp_fast(1.0f + __expf(2.0f * x)); }

__device__ __forceinline__ void split2(float4 u0, float4 u1, f16x8& hi, f16x8& lo) {
    float x[8] = {u0.x, u0.y, u0.z, u0.w, u1.x, u1.y, u1.z, u1.w};
    #pragma unroll
    for (int e = 0; e < 8; ++e) {
        _Float16 h = (_Float16)x[e];
        hi[e] = h;
        lo[e] = (_Float16)(x[e] - (float)h);
    }
}
// scaled variant: lo is stored *1024 so residuals stay in f16 normal range
__device__ __forceinline__ void split2s(float4 u0, float4 u1, f16x8& hi, f16x8& lo) {
    float x[8] = {u0.x, u0.y, u0.z, u0.w, u1.x, u1.y, u1.z, u1.w};
    #pragma unroll
    for (int e = 0; e < 8; ++e) {
        _Float16 h = (_Float16)x[e];
        hi[e] = h;
        lo[e] = (_Float16)((x[e] - (float)h) * S10);
    }
}
__device__ __forceinline__ void split1(float x, _Float16& hi, _Float16& lo) {
    hi = (_Float16)x;
    lo = (_Float16)(x - (float)hi);
}

// lane ^ 32 combine on the VALU pipe (keeps the LDS pipe free)
__device__ __forceinline__ float xsum32(float v) {
#if __has_builtin(__builtin_amdgcn_permlane32_swap)
    auto r = __builtin_amdgcn_permlane32_swap(__float_as_uint(v), __float_as_uint(v), false, false);
    return __uint_as_float(r[0]) + __uint_as_float(r[1]);
#else
    return v + __shfl_xor(v, 32, 64);
#endif
}

// Barrier WITHOUT the vmcnt(0) drain __syncthreads would emit: global stores
// (out[]) are fire-and-forget (nothing reads them), so only LDS ops need to
// complete before waves cross.
__device__ __forceinline__ void step_barrier() {
    __builtin_amdgcn_sched_barrier(0);
    asm volatile("s_waitcnt lgkmcnt(0)" ::: "memory");
    __builtin_amdgcn_s_barrier();
    asm volatile("" ::: "memory");
    __builtin_amdgcn_sched_barrier(0);
}

__global__ __launch_bounds__(1024)
void gru_title(const float* __restrict__ img,
               const float* __restrict__ l1w,
               const float* __restrict__ l1b,
               const float* __restrict__ wih,
               const float* __restrict__ whh,
               const float* __restrict__ bih,
               const float* __restrict__ bhh,
               const float* __restrict__ l2w,
               const float* __restrict__ l2b,
               float* __restrict__ out,
               float* __restrict__ lens)
{
    // M-packed A layout (proven in R4): value (m,k,hi) at row 16*((k>>3)&3)+m,
    // lo at +8; f16 col 8*(k>>5)+(k&7). A-frag read = row=lane, col=8*kt.
    __shared__ alignas(16) _Float16 x2 [2][64][XR];   // h: hi rows 0-7, lo rows 8-15 per 16-group
    __shared__ alignas(16) _Float16 l2v[2][64][XR];   // leaky(h), same layout
    __shared__ alignas(16) _Float16 bcS[2][6][4][4][16][8]; // chars weights hi(0)/lo(1), 48 KB
    __shared__ alignas(16) float    gEx[4096];        // gate exchange [m][i][g], XOR ((m&3)<<5)
    __shared__ alignas(16) float    scr[2048];        // chs[2][8][128]  UNION  xsP[2][8][128]
    __shared__ alignas(16) float    xs0[NB][HH];      // x0 (t=0 path)
    __shared__ int sh_st[4];                          // stable flags, 4-slot rotation

    const int tid  = threadIdx.x;
    const int b0   = blockIdx.x * NB;
    const int w    = tid >> 6;     // wave 0..15
    const int lane = tid & 63;
    const int lm   = lane & 15;
    const int lq   = lane >> 4;
    const int c8   = w & 7;        // i-chunk [16*c8, 16*c8+16)
    const int r8   = w >> 3;       // gate-pair half: 0 -> gates {r,z}, 1 -> {n_i,n_h}
    const int ic2  = 16 * c8 + lm;

    // ---- gate weights: this wave owns gates {2r8, 2r8+1} for chunk c8 ----
    // g=0: r (wih+whh fused, x==h for t>=1); g=1: z (fused); g=2: n_i; g=3: n_h
    f16x8 bh[2][4], bl[2][4];
    float gb[2];
    #pragma unroll
    for (int gl = 0; gl < 2; ++gl) {
        const int g2 = 2 * r8 + gl;
        const float* r0;
        const float* r1 = nullptr;
        float bsum;
        if (g2 == 0)      { r0 = wih + (size_t)ic2 * HH;         r1 = whh + (size_t)ic2 * HH;         bsum = bih[ic2] + bhh[ic2]; }
        else if (g2 == 1) { r0 = wih + (size_t)(128 + ic2) * HH; r1 = whh + (size_t)(128 + ic2) * HH; bsum = bih[128 + ic2] + bhh[128 + ic2]; }
        else if (g2 == 2) { r0 = wih + (size_t)(256 + ic2) * HH;                                      bsum = bih[256 + ic2]; }
        else              { r0 = whh + (size_t)(256 + ic2) * HH;                                      bsum = bhh[256 + ic2]; }
        gb[gl] = bsum;
        #pragma unroll
        for (int kt = 0; kt < 4; ++kt) {
            const int k0 = 32 * kt + 8 * lq;
            float4 u0 = *(const float4*)(r0 + k0);
            float4 u1 = *(const float4*)(r0 + k0 + 4);
            if (r1) {
                float4 e0 = *(const float4*)(r1 + k0);
                float4 e1 = *(const float4*)(r1 + k0 + 4);
                u0.x += e0.x; u0.y += e0.y; u0.z += e0.z; u0.w += e0.w;
                u1.x += e1.x; u1.y += e1.y; u1.z += e1.z; u1.w += e1.w;
            }
            split2(u0, u1, bh[gl][kt], bl[gl][kt]);
        }
    }

    // ---- chars: waves 1..6 own tile ct = w-1 (weights live in LDS) ----
    const int ct = (w >= 1 && w <= 6) ? (w - 1) : -1;
    float cb = 0.f;
    if (ct >= 0) cb = l2b[16 * ct + lm];

    // stage chars weights (hi + lo planes) in LDS; all threads help
    for (int idx = tid; idx < 6 * 4 * 4 * 16; idx += 1024) {
        int t_  = idx;
        int lm_ = t_ & 15; t_ >>= 4;
        int lq_ = t_ & 3;  t_ >>= 2;
        int kt_ = t_ & 3;  t_ >>= 2;
        int ct_ = t_;                       // 0..5
        const int n  = 16 * ct_ + lm_;
        const int k0 = 32 * kt_ + 8 * lq_;
        #pragma unroll
        for (int e = 0; e < 8; ++e) {
            float v = l2w[(size_t)n * HH + k0 + e];
            _Float16 hi = (_Float16)v;
            bcS[0][ct_][kt_][lq_][lm_][e] = hi;
            bcS[1][ct_][kt_][lq_][lm_][e] = (_Float16)(v - (float)hi);
        }
    }

    if (tid < 4) sh_st[tid] = 1;

    // ---- prologue: x0 = leaky(img @ l1w.T + l1b), hi/lo f16 MFMA, K split by r8 ----
    {
        const int m8 = lm & 7;
        const float* arow = img + (size_t)(b0 + m8) * DD + 8 * lq + 2048 * r8;
        const float* brow = l1w + (size_t)ic2 * DD + 8 * lq + 2048 * r8;
        f32x4 z4 = {0.f, 0.f, 0.f, 0.f};
        f32x4 accP0 = z4, accP1 = z4, accQ0 = z4, accQ1 = z4;
        auto ptile = [&](int kt, f32x4& aP, f32x4& aQ) {
            float4 a0  = *(const float4*)(arow + 32 * kt);
            float4 a1  = *(const float4*)(arow + 32 * kt + 4);
            float4 bb0 = *(const float4*)(brow + 32 * kt);
            float4 bb1 = *(const float4*)(brow + 32 * kt + 4);
            f16x8 ah, al, bhf, blf;
            split2s(a0, a1, ah, al);
            split2s(bb0, bb1, bhf, blf);
            f16x8 af = (lm >= 8) ? al : ah;   // lanes lm>=8 carry scaled-lo rows
            aP = __builtin_amdgcn_mfma_f32_16x16x32_f16(af, bhf, aP, 0, 0, 0);
            aQ = __builtin_amdgcn_mfma_f32_16x16x32_f16(af, blf, aQ, 0, 0, 0);
        };
        #pragma unroll 2
        for (int kt = 0; kt < 64; kt += 2) {
            ptile(kt,     accP0, accQ0);
            ptile(kt + 1, accP1, accQ1);
        }
        f32x4 P = accP0 + accP1;
        f32x4 Q = accQ0 + accQ1;
        const float sP = (lane < 32) ? 1.0f : IS10;
        const float sQ = (lane < 32) ? IS10 : IS20;
        float s0 = xsum32(P[0] * sP + Q[0] * sQ);
        float s1 = xsum32(P[1] * sP + Q[1] * sQ);
        float s2 = xsum32(P[2] * sP + Q[2] * sQ);
        float s3 = xsum32(P[3] * sP + Q[3] * sQ);
        if (lane < 32) {     // rows 4lq+reg cover m=0..7; partial for this K half
            float vv[4] = {s0, s1, s2, s3};
            #pragma unroll
            for (int reg = 0; reg < 4; ++reg)
                scr[r8 * 1024 + (4 * lq + reg) * 128 + ic2] = vv[reg];
        }
    }
    __syncthreads();
    {   // combine K halves + bias + leaky: one (m,c) per thread
        const int m = tid >> 7, c = tid & 127;
        float v = scr[m * 128 + c] + scr[1024 + m * 128 + c] + l1b[c];
        xs0[m][c] = (v >= 0.f) ? v : 0.01f * v;
    }
    __syncthreads();

    // phase-A C-row ownership (same as R4): lane holds rows mA, mA+1
    const int mA = (lane < 32) ? 4 * lq : 4 * (lq - 2) + 2;

    // phase-B ownership: one (mB, iB) pair per lane; mB wave-uniform
    const int mB  = w >> 1;
    const int iB  = 64 * (w & 1) + lane;
    const int rBq = 16 * ((iB >> 3) & 3);
    const int cBq = 8 * (iB >> 5) + (iB & 7);
    const unsigned gRd = (unsigned)(mB * 2048 + iB * 16) ^ ((unsigned)(mB & 3) << 5);

    float hreg = 0.f;
    int  len   = TT;
    bool found = false;
    int  tex   = TT;

    // chars(t-1): M-packed MFMA from l2v[slot]; weights from LDS
    auto chars_mfma = [&](int slot, f32x4& cA, f32x4& cB) {
        #pragma unroll
        for (int kt = 0; kt < 4; ++kt) {
            f16x8 cf = *(const f16x8*)&l2v[slot][lane][8 * kt];
            f16x8 bH = *(const f16x8*)&bcS[0][ct][kt][lq][lm][0];
            f16x8 bL = *(const f16x8*)&bcS[1][ct][kt][lq][lm][0];
            f32x4& a = (kt < 2) ? cA : cB;
            a = __builtin_amdgcn_mfma_f32_16x16x32_f16(cf, bH, a, 0, 0, 0);
            a = __builtin_amdgcn_mfma_f32_16x16x32_f16(cf, bL, a, 0, 0, 0);
        }
    };
    auto chars_commit = [&](int slot, f32x4 cA, f32x4 cB) {
        f32x4 ca = cA + cB;
        const int n = 16 * ct + lm;
        float s0 = xsum32(ca[0]);
        float s1 = xsum32(ca[1]);
        float s2 = xsum32(ca[2]);
        float s3 = xsum32(ca[3]);
        scr[slot * 1024 + mA * 128 + n]       = ((lane < 32) ? s0 : s2) + cb;
        scr[slot * 1024 + (mA + 1) * 128 + n] = ((lane < 32) ? s1 : s3) + cb;
    };

    // full-row normalized write of chars(tme) for batch row r from scr slot
    auto outrow = [&](int slot, int tme, int r) {
        const float* cr = &scr[slot * 1024 + r * 128];
        float a0 = cr[lane];
        float a1 = cr[32 + lane];
        float a2 = cr[64 + lane];
        float mx = fmaxf(fmaxf(a0, a1), a2);
        mx = fmaxf(mx, __shfl_xor(mx, 16, 32));
        mx = fmaxf(mx, __shfl_xor(mx, 8, 32));
        mx = fmaxf(mx, __shfl_xor(mx, 4, 32));
        mx = fmaxf(mx, __shfl_xor(mx, 2, 32));
        mx = fmaxf(mx, __shfl_xor(mx, 1, 32));
        float q0 = a0 / mx;   // exact IEEE divide (q52 == 1.0f check + stored bits)
        float q1 = a1 / mx;
        float q2 = a2 / mx;
        if (lane < 32) {
            size_t base = ((size_t)(b0 + r) * TT + tme) * CC;
            out[base + lane]      = (q0 > THRV) ? q0 : 0.f;
            out[base + 32 + lane] = (q1 > THRV) ? q1 : 0.f;
            out[base + 64 + lane] = (q2 > THRV) ? q2 : 0.f;
        }
        float q52 = __shfl(q1, 20, 64);   // element 52 = 32 + 20
        if (!found && q52 == 1.0f) { found = true; len = tme + 1; }
    };

    for (int t = 0; t < TT; ++t) {
        const int pr = (t + 1) & 1;   // read slot ((t-1)&1)
        const int pc = t & 1;         // write slot

        // ================= phase A =================
        if (t == 0) {
            // exact-f32 gates from xs0 -> gEx (wih only for g<3; h=0 -> g=3 bias)
            if (tid < 512) {
                const int g = tid >> 7;        // 0..3
                const int i = tid & 127;
                float bsum;
                if (g == 0)      bsum = bih[i] + bhh[i];
                else if (g == 1) bsum = bih[128 + i] + bhh[128 + i];
                else if (g == 2) bsum = bih[256 + i];
                else             bsum = bhh[256 + i];
                float accT[NB];
                #pragma unroll
                for (int m = 0; m < NB; ++m) accT[m] = bsum;
                if (g < 3) {
                    const float4* wp = (const float4*)(wih + (size_t)(128 * g + i) * HH);
                    #pragma unroll
                    for (int k = 0; k < HH / 4; ++k) {
                        float4 wv = wp[k];
                        #pragma unroll
                        for (int m = 0; m < NB; ++m) {
                            float4 x = *(const float4*)&xs0[m][4 * k];
                            accT[m] += wv.x * x.x + wv.y * x.y + wv.z * x.z + wv.w * x.w;
                        }
                    }
                }
                #pragma unroll
                for (int m = 0; m < NB; ++m) {
                    unsigned off = (unsigned)(m * 2048 + i * 16 + g * 4) ^ ((unsigned)(m & 3) << 5);
                    *(float*)((char*)gEx + off) = accT[m];
                }
            }
        } else {
            // gates first: A-frag loads + 16 MFMA (2 gates, hi/lo packed)
            f16x8 af0 = *(const f16x8*)&x2[pr][lane][0];
            f16x8 af1 = *(const f16x8*)&x2[pr][lane][8];
            f16x8 af2 = *(const f16x8*)&x2[pr][lane][16];
            f16x8 af3 = *(const f16x8*)&x2[pr][lane][24];
            f32x4 z4 = {0.f, 0.f, 0.f, 0.f};
            f32x4 aA[2] = {z4, z4};
            f32x4 aB[2] = {z4, z4};
            #pragma unroll
            for (int gl = 0; gl < 2; ++gl) {
                aA[gl] = __builtin_amdgcn_mfma_f32_16x16x32_f16(af0, bh[gl][0], aA[gl], 0, 0, 0);
                aA[gl] = __builtin_amdgcn_mfma_f32_16x16x32_f16(af0, bl[gl][0], aA[gl], 0, 0, 0);
                aA[gl] = __builtin_amdgcn_mfma_f32_16x16x32_f16(af1, bh[gl][1], aA[gl], 0, 0, 0);
                aA[gl] = __builtin_amdgcn_mfma_f32_16x16x32_f16(af1, bl[gl][1], aA[gl], 0, 0, 0);
                aB[gl] = __builtin_amdgcn_mfma_f32_16x16x32_f16(af2, bh[gl][2], aB[gl], 0, 0, 0);
                aB[gl] = __builtin_amdgcn_mfma_f32_16x16x32_f16(af2, bl[gl][2], aB[gl], 0, 0, 0);
                aB[gl] = __builtin_amdgcn_mfma_f32_16x16x32_f16(af3, bh[gl][3], aB[gl], 0, 0, 0);
                aB[gl] = __builtin_amdgcn_mfma_f32_16x16x32_f16(af3, bl[gl][3], aB[gl], 0, 0, 0);
            }
            // chars(t-1) under the gate-MFMA shadow (waves 1..6)
            f32x4 cc0 = z4, cc1 = z4;
            if (ct >= 0) chars_mfma(pr, cc0, cc1);
            // gate combine (hi rows + lo rows via lane^32) + exchange write
            float G[2][2];
            #pragma unroll
            for (int gl = 0; gl < 2; ++gl) {
                f32x4 s4 = aA[gl] + aB[gl];
                float s0 = xsum32(s4[0]);
                float s1 = xsum32(s4[1]);
                float s2 = xsum32(s4[2]);
                float s3 = xsum32(s4[3]);
                G[gl][0] = ((lane < 32) ? s0 : s2) + gb[gl];
                G[gl][1] = ((lane < 32) ? s1 : s3) + gb[gl];
            }
            #pragma unroll
            for (int s = 0; s < 2; ++s) {
                const int m = mA + s;
                unsigned off = (unsigned)(m * 2048 + ic2 * 16 + r8 * 8) ^ ((unsigned)(m & 3) << 5);
                f32x2 v2 = {G[0][s], G[1][s]};
                *(f32x2*)((char*)gEx + off) = v2;
            }
            if (ct >= 0) chars_commit(pr, cc0, cc1);
        }
        step_barrier();   // bar1: gEx (and chs) ready

        // ================= phase B =================
        {
            float4 g4 = *(const float4*)((const char*)gEx + gRd);
            float r = sigm(g4.x);
            float z = sigm(g4.y);
            float n = ftanh(g4.z + r * g4.w);
            float hp = (t == 0) ? 0.f : hreg;
            float h  = (1.f - z) * n + z * hp;
            bool chg = (t < 2) | (fabsf(h - hp) > HEPS);
            hreg = h;
            float lv = (h >= 0.f) ? h : 0.01f * h;
            _Float16 a, b;
            split1(h, a, b);
            x2[pc][rBq + mB][cBq]     = a;
            x2[pc][rBq + 8 + mB][cBq] = b;
            split1(lv, a, b);
            l2v[pc][rBq + mB][cBq]     = a;
            l2v[pc][rBq + 8 + mB][cBq] = b;
            if (chg) sh_st[t & 3] = 0;          // benign multi-writer race
        }
        if (w >= 8 && t >= 2) outrow(pc, t - 2, w - 8);
        if (tid == 0) sh_st[(t + 2) & 3] = 1;   // slot for t+2
        step_barrier();   // bar2: x2/l2v ready for next step
        if (t >= 2 && sh_st[t & 3]) { tex = t; break; }
    }

    if (tex == TT) {
        // natural end: write chars(TT-2); compute + write chars(TT-1)
        const int pl = (TT - 1) & 1;
        if (ct >= 0) {
            f32x4 z4 = {0.f, 0.f, 0.f, 0.f};
            f32x4 cc0 = z4, cc1 = z4;
            chars_mfma(pl, cc0, cc1);
            chars_commit(pl, cc0, cc1);
        }
        if (w >= 8) outrow(TT & 1, TT - 2, w - 8);
        __syncthreads();
        if (w >= 8) outrow(pl, TT - 1, w - 8);
    } else if (w >= 8) {
        // frozen from tex: loop wrote times 0..tex-2. Write chars(tex-1), then
        // fill [tex, TT) with the two parity patterns (zeros included), stride-2.
        const int r = w - 8;
        outrow((tex + 1) & 1, tex - 1, r);
        size_t rowbase = (size_t)(b0 + r) * TT * CC;
        #pragma unroll
        for (int p = 0; p < 2; ++p) {
            const float* cr = &scr[p * 1024 + r * 128];
            float a0 = cr[lane];
            float a1 = cr[32 + lane];
            float a2 = cr[64 + lane];
            float mx = fmaxf(fmaxf(a0, a1), a2);
            mx = fmaxf(mx, __shfl_xor(mx, 16, 32));
            mx = fmaxf(mx, __shfl_xor(mx, 8, 32));
            mx = fmaxf(mx, __shfl_xor(mx, 4, 32));
            mx = fmaxf(mx, __shfl_xor(mx, 2, 32));
            mx = fmaxf(mx, __shfl_xor(mx, 1, 32));
            const int u0 = tex + (((tex & 1) == p) ? 0 : 1);
            if (lane < 32) {
                float q0 = a0 / mx;
                float q1 = a1 / mx;
                float q2 = a2 / mx;
                float w0v = (q0 > THRV) ? q0 : 0.f;
                float w1v = (q1 > THRV) ? q1 : 0.f;
                float w2v = (q2 > THRV) ? q2 : 0.f;
                for (int u = u0; u < TT; u += 2) {
                    out[rowbase + (size_t)u * CC + lane]      = w0v;
                    out[rowbase + (size_t)u * CC + 32 + lane] = w1v;
                    out[rowbase + (size_t)u * CC + 64 + lane] = w2v;
                }
            }
        }
        // lens: frozen pattern's char-52 hit (if any) recorded at tex-2 / tex-1.
    }

    if (w >= 8 && lane == 0) lens[b0 + (w - 8)] = (float)len;
}

extern "C" void kernel_launch(void* const* d_in, const int* in_sizes, int n_in,
                              void* d_out, int out_size, void* d_ws, size_t ws_size,
                              hipStream_t stream)
{
    const float* img = (const float*)d_in[0];
    const float* l1w = (const float*)d_in[1];
    const float* l1b = (const float*)d_in[2];
    const float* wih = (const float*)d_in[3];
    const float* whh = (const float*)d_in[4];
    const float* bih = (const float*)d_in[5];
    const float* bhh = (const float*)d_in[6];
    const float* l2w = (const float*)d_in[7];
    const float* l2b = (const float*)d_in[8];

    float* out  = (float*)d_out;
    float* lens = out + (size_t)2048 * TT * CC;

    // no memset: the kernel writes every title element exactly once
    // (full-row coalesced stores with explicit zeros) and all lens entries.
    gru_title<<<dim3(2048 / NB), dim3(1024), 0, stream>>>(
        img, l1w, l1b, wih, whh, bih, bhh, l2w, l2b, out, lens);
}

// Round 6
// 572.788 us; speedup vs baseline: 1.9749x; 1.1062x over previous
//
#include <hip/hip_runtime.h>
#include <math.h>

#define NB   8
#define TT   400
#define HH   128
#define CC   96
#define DD   4096
#define THRV (1.0f - 1e-5f)
#define XR   40      // f16 row pad: 80 B rows (5*16B -> b128-aligned, clean bank walk)
#define HEPS 4e-6f   // convergence tolerance (same class-proven margin as before)
#define S10  1024.0f            // lo-split scale (keeps lo out of f16 subnormals)
#define IS10 0.0009765625f      // 2^-10
#define IS20 9.5367431640625e-07f  // 2^-20

typedef _Float16 f16x8 __attribute__((ext_vector_type(8)));
typedef float    f32x4 __attribute__((ext_vector_type(4)));
typedef float    f32x2 __attribute__((ext_vector_type(2)));

__device__ __forceinline__ float rcp_fast(float x) {
#if __has_builtin(__builtin_amdgcn_rcpf)
    return __builtin_amdgcn_rcpf(x);
#else
    return 1.0f / x;
#endif
}
// v_exp_f32-based sigmoid/tanh: ~1e-7 err, far inside the proven 5e-5 margin.
__device__ __forceinline__ float sigm(float v)  { return rcp_fast(1.0f + __expf(-v)); }
__device__ __forceinline__ float ftanh(float x) { return 1.0f - 2.0f * rcp_fast(1.0f + __expf(2.0f * x)); }

__device__ __forceinline__ void split2(float4 u0, float4 u1, f16x8& hi, f16x8& lo) {
    float x[8] = {u0.x, u0.y, u0.z, u0.w, u1.x, u1.y, u1.z, u1.w};
    #pragma unroll
    for (int e = 0; e < 8; ++e) {
        _Float16 h = (_Float16)x[e];
        hi[e] = h;
        lo[e] = (_Float16)(x[e] - (float)h);
    }
}
// scaled variant: lo is stored *1024 so residuals stay in f16 normal range
__device__ __forceinline__ void split2s(float4 u0, float4 u1, f16x8& hi, f16x8& lo) {
    float x[8] = {u0.x, u0.y, u0.z, u0.w, u1.x, u1.y, u1.z, u1.w};
    #pragma unroll
    for (int e = 0; e < 8; ++e) {
        _Float16 h = (_Float16)x[e];
        hi[e] = h;
        lo[e] = (_Float16)((x[e] - (float)h) * S10);
    }
}
__device__ __forceinline__ void split1(float x, _Float16& hi, _Float16& lo) {
    hi = (_Float16)x;
    lo = (_Float16)(x - (float)hi);
}

// lane ^ 32 combine on the VALU pipe (keeps the LDS pipe free)
__device__ __forceinline__ float xsum32(float v) {
#if __has_builtin(__builtin_amdgcn_permlane32_swap)
    auto r = __builtin_amdgcn_permlane32_swap(__float_as_uint(v), __float_as_uint(v), false, false);
    return __uint_as_float(r[0]) + __uint_as_float(r[1]);
#else
    return v + __shfl_xor(v, 32, 64);
#endif
}

// Barrier WITHOUT the vmcnt(0) drain __syncthreads would emit: global stores
// (out[]) are fire-and-forget (nothing reads them), so only LDS ops need to
// complete before waves cross.
__device__ __forceinline__ void step_barrier() {
    __builtin_amdgcn_sched_barrier(0);
    asm volatile("s_waitcnt lgkmcnt(0)" ::: "memory");
    __builtin_amdgcn_s_barrier();
    asm volatile("" ::: "memory");
    __builtin_amdgcn_sched_barrier(0);
}

__global__ __launch_bounds__(1024)
void gru_title(const float* __restrict__ img,
               const float* __restrict__ l1w,
               const float* __restrict__ l1b,
               const float* __restrict__ wih,
               const float* __restrict__ whh,
               const float* __restrict__ bih,
               const float* __restrict__ bhh,
               const float* __restrict__ l2w,
               const float* __restrict__ l2b,
               float* __restrict__ out,
               float* __restrict__ lens)
{
    // M-packed A layout (proven in R4/R5): value (m,k,hi) at row 16*((k>>3)&3)+m,
    // lo at +8; f16 col 8*(k>>5)+(k&7). A-frag read = row=lane, col=8*kt.
    __shared__ alignas(16) _Float16 x2 [2][64][XR];   // h: hi rows 0-7, lo rows 8-15 per 16-group
    __shared__ alignas(16) _Float16 l2v[2][64][XR];   // leaky(h), same layout
    __shared__ alignas(16) _Float16 bcS[2][6][4][4][16][8]; // chars weights hi(0)/lo(1), 48 KB
    __shared__ alignas(16) float    gEx[4096];        // gate exchange [m][i][g], XOR ((m&3)<<5)
    __shared__ alignas(16) float    scr[2048];        // chs[2][8][128]  UNION  xsP[2][8][128]
    __shared__ alignas(16) float    xs0[NB][HH];      // x0 (t=0 path)
    __shared__ int sh_st[4];                          // stable flags, 4-slot rotation

    const int tid  = threadIdx.x;
    const int b0   = blockIdx.x * NB;
    const int w    = tid >> 6;     // wave 0..15
    const int lane = tid & 63;
    const int lm   = lane & 15;
    const int lq   = lane >> 4;
    const int c8   = w & 7;        // i-chunk [16*c8, 16*c8+16)
    const int r8   = w >> 3;       // gate-pair half: 0 -> gates {r,z}, 1 -> {n_i,n_h}
    const int ic2  = 16 * c8 + lm;

    // ---- gate weights: this wave owns gates {2r8, 2r8+1} for chunk c8 ----
    // g=0: r (wih+whh fused, x==h for t>=1); g=1: z (fused); g=2: n_i; g=3: n_h
    // B kept HI-ONLY: the M-pack MFMA already yields ah*bh + al*bh; the dropped
    // ah*bl term is ~6e-5 rms on a gate pre-act, reaching chars only through the
    // damped recurrence (est <=1e-4 on q, vs ~2.5e-4 proven argmax margin).
    f16x8 bh[2][4];
    float gb[2];
    #pragma unroll
    for (int gl = 0; gl < 2; ++gl) {
        const int g2 = 2 * r8 + gl;
        const float* r0;
        const float* r1 = nullptr;
        float bsum;
        if (g2 == 0)      { r0 = wih + (size_t)ic2 * HH;         r1 = whh + (size_t)ic2 * HH;         bsum = bih[ic2] + bhh[ic2]; }
        else if (g2 == 1) { r0 = wih + (size_t)(128 + ic2) * HH; r1 = whh + (size_t)(128 + ic2) * HH; bsum = bih[128 + ic2] + bhh[128 + ic2]; }
        else if (g2 == 2) { r0 = wih + (size_t)(256 + ic2) * HH;                                      bsum = bih[256 + ic2]; }
        else              { r0 = whh + (size_t)(256 + ic2) * HH;                                      bsum = bhh[256 + ic2]; }
        gb[gl] = bsum;
        #pragma unroll
        for (int kt = 0; kt < 4; ++kt) {
            const int k0 = 32 * kt + 8 * lq;
            float4 u0 = *(const float4*)(r0 + k0);
            float4 u1 = *(const float4*)(r0 + k0 + 4);
            if (r1) {
                float4 e0 = *(const float4*)(r1 + k0);
                float4 e1 = *(const float4*)(r1 + k0 + 4);
                u0.x += e0.x; u0.y += e0.y; u0.z += e0.z; u0.w += e0.w;
                u1.x += e1.x; u1.y += e1.y; u1.z += e1.z; u1.w += e1.w;
            }
            f16x8 hiv, lov;
            split2(u0, u1, hiv, lov);
            bh[gl][kt] = hiv;     // lo discarded (DCE'd)
        }
    }

    // ---- chars: waves 1..6 own tile ct = w-1 (weights live in LDS; EXACT hi+lo) ----
    const int ct = (w >= 1 && w <= 6) ? (w - 1) : -1;
    float cb = 0.f;
    if (ct >= 0) cb = l2b[16 * ct + lm];

    // stage chars weights (hi + lo planes) in LDS; all threads help
    for (int idx = tid; idx < 6 * 4 * 4 * 16; idx += 1024) {
        int t_  = idx;
        int lm_ = t_ & 15; t_ >>= 4;
        int lq_ = t_ & 3;  t_ >>= 2;
        int kt_ = t_ & 3;  t_ >>= 2;
        int ct_ = t_;                       // 0..5
        const int n  = 16 * ct_ + lm_;
        const int k0 = 32 * kt_ + 8 * lq_;
        #pragma unroll
        for (int e = 0; e < 8; ++e) {
            float v = l2w[(size_t)n * HH + k0 + e];
            _Float16 hi = (_Float16)v;
            bcS[0][ct_][kt_][lq_][lm_][e] = hi;
            bcS[1][ct_][kt_][lq_][lm_][e] = (_Float16)(v - (float)hi);
        }
    }

    if (tid < 4) sh_st[tid] = 1;

    // ---- prologue: x0 = leaky(img @ l1w.T + l1b), hi/lo f16 MFMA, K split by r8 ----
    {
        const int m8 = lm & 7;
        const float* arow = img + (size_t)(b0 + m8) * DD + 8 * lq + 2048 * r8;
        const float* brow = l1w + (size_t)ic2 * DD + 8 * lq + 2048 * r8;
        f32x4 z4 = {0.f, 0.f, 0.f, 0.f};
        f32x4 accP0 = z4, accP1 = z4, accQ0 = z4, accQ1 = z4;
        auto ptile = [&](int kt, f32x4& aP, f32x4& aQ) {
            float4 a0  = *(const float4*)(arow + 32 * kt);
            float4 a1  = *(const float4*)(arow + 32 * kt + 4);
            float4 bb0 = *(const float4*)(brow + 32 * kt);
            float4 bb1 = *(const float4*)(brow + 32 * kt + 4);
            f16x8 ah, al, bhf, blf;
            split2s(a0, a1, ah, al);
            split2s(bb0, bb1, bhf, blf);
            f16x8 af = (lm >= 8) ? al : ah;   // lanes lm>=8 carry scaled-lo rows
            aP = __builtin_amdgcn_mfma_f32_16x16x32_f16(af, bhf, aP, 0, 0, 0);
            aQ = __builtin_amdgcn_mfma_f32_16x16x32_f16(af, blf, aQ, 0, 0, 0);
        };
        #pragma unroll 2
        for (int kt = 0; kt < 64; kt += 2) {
            ptile(kt,     accP0, accQ0);
            ptile(kt + 1, accP1, accQ1);
        }
        f32x4 P = accP0 + accP1;
        f32x4 Q = accQ0 + accQ1;
        const float sP = (lane < 32) ? 1.0f : IS10;
        const float sQ = (lane < 32) ? IS10 : IS20;
        float s0 = xsum32(P[0] * sP + Q[0] * sQ);
        float s1 = xsum32(P[1] * sP + Q[1] * sQ);
        float s2 = xsum32(P[2] * sP + Q[2] * sQ);
        float s3 = xsum32(P[3] * sP + Q[3] * sQ);
        if (lane < 32) {     // rows 4lq+reg cover m=0..7; partial for this K half
            float vv[4] = {s0, s1, s2, s3};
            #pragma unroll
            for (int reg = 0; reg < 4; ++reg)
                scr[r8 * 1024 + (4 * lq + reg) * 128 + ic2] = vv[reg];
        }
    }
    __syncthreads();
    {   // combine K halves + bias + leaky: one (m,c) per thread
        const int m = tid >> 7, c = tid & 127;
        float v = scr[m * 128 + c] + scr[1024 + m * 128 + c] + l1b[c];
        xs0[m][c] = (v >= 0.f) ? v : 0.01f * v;
    }
    __syncthreads();

    // phase-A C-row ownership (same as R4): lane holds rows mA, mA+1
    const int mA = (lane < 32) ? 4 * lq : 4 * (lq - 2) + 2;

    // phase-B ownership: one (mB, iB) pair per lane; mB wave-uniform
    const int mB  = w >> 1;
    const int iB  = 64 * (w & 1) + lane;
    const int rBq = 16 * ((iB >> 3) & 3);
    const int cBq = 8 * (iB >> 5) + (iB & 7);
    const unsigned gRd = (unsigned)(mB * 2048 + iB * 16) ^ ((unsigned)(mB & 3) << 5);

    float hreg = 0.f;
    int  len   = TT;
    bool found = false;
    int  tex   = TT;

    // chars(t-1): M-packed MFMA from l2v[slot]; weights from LDS (exact hi+lo)
    auto chars_mfma = [&](int slot, f32x4& cA, f32x4& cB) {
        #pragma unroll
        for (int kt = 0; kt < 4; ++kt) {
            f16x8 cf = *(const f16x8*)&l2v[slot][lane][8 * kt];
            f16x8 bH = *(const f16x8*)&bcS[0][ct][kt][lq][lm][0];
            f16x8 bL = *(const f16x8*)&bcS[1][ct][kt][lq][lm][0];
            f32x4& a = (kt < 2) ? cA : cB;
            a = __builtin_amdgcn_mfma_f32_16x16x32_f16(cf, bH, a, 0, 0, 0);
            a = __builtin_amdgcn_mfma_f32_16x16x32_f16(cf, bL, a, 0, 0, 0);
        }
    };
    auto chars_commit = [&](int slot, f32x4 cA, f32x4 cB) {
        f32x4 ca = cA + cB;
        const int n = 16 * ct + lm;
        float s0 = xsum32(ca[0]);
        float s1 = xsum32(ca[1]);
        float s2 = xsum32(ca[2]);
        float s3 = xsum32(ca[3]);
        scr[slot * 1024 + mA * 128 + n]       = ((lane < 32) ? s0 : s2) + cb;
        scr[slot * 1024 + (mA + 1) * 128 + n] = ((lane < 32) ? s1 : s3) + cb;
    };

    // full-row normalized write of chars(tme) for batch row r from scr slot
    auto outrow = [&](int slot, int tme, int r) {
        const float* cr = &scr[slot * 1024 + r * 128];
        float a0 = cr[lane];
        float a1 = cr[32 + lane];
        float a2 = cr[64 + lane];
        float mx = fmaxf(fmaxf(a0, a1), a2);
        mx = fmaxf(mx, __shfl_xor(mx, 16, 32));
        mx = fmaxf(mx, __shfl_xor(mx, 8, 32));
        mx = fmaxf(mx, __shfl_xor(mx, 4, 32));
        mx = fmaxf(mx, __shfl_xor(mx, 2, 32));
        mx = fmaxf(mx, __shfl_xor(mx, 1, 32));
        float q0 = a0 / mx;   // exact IEEE divide (q52 == 1.0f check + stored bits)
        float q1 = a1 / mx;
        float q2 = a2 / mx;
        if (lane < 32) {
            size_t base = ((size_t)(b0 + r) * TT + tme) * CC;
            out[base + lane]      = (q0 > THRV) ? q0 : 0.f;
            out[base + 32 + lane] = (q1 > THRV) ? q1 : 0.f;
            out[base + 64 + lane] = (q2 > THRV) ? q2 : 0.f;
        }
        float q52 = __shfl(q1, 20, 64);   // element 52 = 32 + 20
        if (!found && q52 == 1.0f) { found = true; len = tme + 1; }
    };

    for (int t = 0; t < TT; ++t) {
        const int pr = (t + 1) & 1;   // read slot ((t-1)&1)
        const int pc = t & 1;         // write slot

        // ================= phase A =================
        if (t == 0) {
            // exact-f32 gates from xs0 -> gEx (wih only for g<3; h=0 -> g=3 bias)
            if (tid < 512) {
                const int g = tid >> 7;        // 0..3
                const int i = tid & 127;
                float bsum;
                if (g == 0)      bsum = bih[i] + bhh[i];
                else if (g == 1) bsum = bih[128 + i] + bhh[128 + i];
                else if (g == 2) bsum = bih[256 + i];
                else             bsum = bhh[256 + i];
                float accT[NB];
                #pragma unroll
                for (int m = 0; m < NB; ++m) accT[m] = bsum;
                if (g < 3) {
                    const float4* wp = (const float4*)(wih + (size_t)(128 * g + i) * HH);
                    #pragma unroll
                    for (int k = 0; k < HH / 4; ++k) {
                        float4 wv = wp[k];
                        #pragma unroll
                        for (int m = 0; m < NB; ++m) {
                            float4 x = *(const float4*)&xs0[m][4 * k];
                            accT[m] += wv.x * x.x + wv.y * x.y + wv.z * x.z + wv.w * x.w;
                        }
                    }
                }
                #pragma unroll
                for (int m = 0; m < NB; ++m) {
                    unsigned off = (unsigned)(m * 2048 + i * 16 + g * 4) ^ ((unsigned)(m & 3) << 5);
                    *(float*)((char*)gEx + off) = accT[m];
                }
            }
        } else {
            // gates first: A-frag loads + 8 MFMA (2 gates, hi-B only; M-pack
            // delivers ah*bh + al*bh; 2 chains of depth 2 per gate)
            f16x8 af0 = *(const f16x8*)&x2[pr][lane][0];
            f16x8 af1 = *(const f16x8*)&x2[pr][lane][8];
            f16x8 af2 = *(const f16x8*)&x2[pr][lane][16];
            f16x8 af3 = *(const f16x8*)&x2[pr][lane][24];
            f32x4 z4 = {0.f, 0.f, 0.f, 0.f};
            f32x4 aA[2] = {z4, z4};
            f32x4 aB[2] = {z4, z4};
            #pragma unroll
            for (int gl = 0; gl < 2; ++gl) {
                aA[gl] = __builtin_amdgcn_mfma_f32_16x16x32_f16(af0, bh[gl][0], aA[gl], 0, 0, 0);
                aA[gl] = __builtin_amdgcn_mfma_f32_16x16x32_f16(af1, bh[gl][1], aA[gl], 0, 0, 0);
                aB[gl] = __builtin_amdgcn_mfma_f32_16x16x32_f16(af2, bh[gl][2], aB[gl], 0, 0, 0);
                aB[gl] = __builtin_amdgcn_mfma_f32_16x16x32_f16(af3, bh[gl][3], aB[gl], 0, 0, 0);
            }
            // chars(t-1) under the gate-MFMA shadow (waves 1..6)
            f32x4 cc0 = z4, cc1 = z4;
            if (ct >= 0) chars_mfma(pr, cc0, cc1);
            // gate combine (hi rows + lo rows via lane^32) + exchange write
            float G[2][2];
            #pragma unroll
            for (int gl = 0; gl < 2; ++gl) {
                f32x4 s4 = aA[gl] + aB[gl];
                float s0 = xsum32(s4[0]);
                float s1 = xsum32(s4[1]);
                float s2 = xsum32(s4[2]);
                float s3 = xsum32(s4[3]);
                G[gl][0] = ((lane < 32) ? s0 : s2) + gb[gl];
                G[gl][1] = ((lane < 32) ? s1 : s3) + gb[gl];
            }
            #pragma unroll
            for (int s = 0; s < 2; ++s) {
                const int m = mA + s;
                unsigned off = (unsigned)(m * 2048 + ic2 * 16 + r8 * 8) ^ ((unsigned)(m & 3) << 5);
                f32x2 v2 = {G[0][s], G[1][s]};
                *(f32x2*)((char*)gEx + off) = v2;
            }
            if (ct >= 0) chars_commit(pr, cc0, cc1);
        }
        step_barrier();   // bar1: gEx (and chs) ready

        // ================= phase B =================
        {
            float4 g4 = *(const float4*)((const char*)gEx + gRd);
            float r = sigm(g4.x);
            float z = sigm(g4.y);
            float n = ftanh(g4.z + r * g4.w);
            float hp = (t == 0) ? 0.f : hreg;
            float h  = (1.f - z) * n + z * hp;
            bool chg = (t < 2) | (fabsf(h - hp) > HEPS);
            hreg = h;
            float lv = (h >= 0.f) ? h : 0.01f * h;
            _Float16 a, b;
            split1(h, a, b);
            x2[pc][rBq + mB][cBq]     = a;
            x2[pc][rBq + 8 + mB][cBq] = b;
            split1(lv, a, b);
            l2v[pc][rBq + mB][cBq]     = a;
            l2v[pc][rBq + 8 + mB][cBq] = b;
            if (chg) sh_st[t & 3] = 0;          // benign multi-writer race
        }
        if (w >= 8 && t >= 2) outrow(pc, t - 2, w - 8);
        if (tid == 0) sh_st[(t + 2) & 3] = 1;   // slot for t+2
        step_barrier();   // bar2: x2/l2v ready for next step
        if (t >= 2 && sh_st[t & 3]) { tex = t; break; }
    }

    if (tex == TT) {
        // natural end: write chars(TT-2); compute + write chars(TT-1)
        const int pl = (TT - 1) & 1;
        if (ct >= 0) {
            f32x4 z4 = {0.f, 0.f, 0.f, 0.f};
            f32x4 cc0 = z4, cc1 = z4;
            chars_mfma(pl, cc0, cc1);
            chars_commit(pl, cc0, cc1);
        }
        if (w >= 8) outrow(TT & 1, TT - 2, w - 8);
        __syncthreads();
        if (w >= 8) outrow(pl, TT - 1, w - 8);
    } else if (w >= 8) {
        // frozen from tex: loop wrote times 0..tex-2. Write chars(tex-1), then
        // fill [tex, TT) with the two parity patterns (zeros included), stride-2.
        const int r = w - 8;
        outrow((tex + 1) & 1, tex - 1, r);
        size_t rowbase = (size_t)(b0 + r) * TT * CC;
        #pragma unroll
        for (int p = 0; p < 2; ++p) {
            const float* cr = &scr[p * 1024 + r * 128];
            float a0 = cr[lane];
            float a1 = cr[32 + lane];
            float a2 = cr[64 + lane];
            float mx = fmaxf(fmaxf(a0, a1), a2);
            mx = fmaxf(mx, __shfl_xor(mx, 16, 32));
            mx = fmaxf(mx, __shfl_xor(mx, 8, 32));
            mx = fmaxf(mx, __shfl_xor(mx, 4, 32));
            mx = fmaxf(mx, __shfl_xor(mx, 2, 32));
            mx = fmaxf(mx, __shfl_xor(mx, 1, 32));
            const int u0 = tex + (((tex & 1) == p) ? 0 : 1);
            if (lane < 32) {
                float q0 = a0 / mx;
                float q1 = a1 / mx;
                float q2 = a2 / mx;
                float w0v = (q0 > THRV) ? q0 : 0.f;
                float w1v = (q1 > THRV) ? q1 : 0.f;
                float w2v = (q2 > THRV) ? q2 : 0.f;
                for (int u = u0; u < TT; u += 2) {
                    out[rowbase + (size_t)u * CC + lane]      = w0v;
                    out[rowbase + (size_t)u * CC + 32 + lane] = w1v;
                    out[rowbase + (size_t)u * CC + 64 + lane] = w2v;
                }
            }
        }
        // lens: frozen pattern's char-52 hit (if any) recorded at tex-2 / tex-1.
    }

    if (w >= 8 && lane == 0) lens[b0 + (w - 8)] = (float)len;
}

extern "C" void kernel_launch(void* const* d_in, const int* in_sizes, int n_in,
                              void* d_out, int out_size, void* d_ws, size_t ws_size,
                              hipStream_t stream)
{
    const float* img = (const float*)d_in[0];
    const float* l1w = (const float*)d_in[1];
    const float* l1b = (const float*)d_in[2];
    const float* wih = (const float*)d_in[3];
    const float* whh = (const float*)d_in[4];
    const float* bih = (const float*)d_in[5];
    const float* bhh = (const float*)d_in[6];
    const float* l2w = (const float*)d_in[7];
    const float* l2b = (const float*)d_in[8];

    float* out  = (float*)d_out;
    float* lens = out + (size_t)2048 * TT * CC;

    // no memset: the kernel writes every title element exactly once
    // (full-row coalesced stores with explicit zeros) and all lens entries.
    gru_title<<<dim3(2048 / NB), dim3(1024), 0, stream>>>(
        img, l1w, l1b, wih, whh, bih, bhh, l2w, l2b, out, lens);
}